// Round 12
// baseline (679.378 us; speedup 1.0000x reference)
//
#include <hip/hip_runtime.h>
#include <math.h>

#define NN 10000
#define NE 50000
#define BG 256
#define NNF 11
#define NT 12

typedef unsigned int u32;
typedef __attribute__((ext_vector_type(8))) short short8v;   // 8 bf16 (4 VGPRs)
typedef __attribute__((ext_vector_type(4))) float f32x4;

__device__ __forceinline__ float sigm(float x){ return 1.0f/(1.0f+__expf(-x)); }
__device__ __forceinline__ u32 f2bf(float f){
  u32 u = __float_as_uint(f);
  return (u + 0x7fffu + ((u>>16)&1u)) >> 16;   // RNE
}
__device__ __forceinline__ float bf2f(u32 s){ return __uint_as_float(s<<16); }

// wave-per-node init: h from x, bf16 hi/lo split, hb = h@b1c, m = 0.
__global__ __launch_bounds__(256) void k_h_init(const float* __restrict__ x, float* __restrict__ h,
                         unsigned short* __restrict__ hHi, unsigned short* __restrict__ hLo,
                         const float* __restrict__ b1c, float* __restrict__ hb,
                         float* __restrict__ m){
  __shared__ float sv[8][64];
  int t = threadIdx.x, w = t>>6, lane = t&63;
  int n0 = blockIdx.x*8 + w*2;
  #pragma unroll
  for (int q = 0; q < 2; ++q){
    int n = n0 + q;
    float v = (lane < NNF) ? x[n*NNF + lane] : 0.0f;
    h[n*64+lane] = v;
    u32 hv = f2bf(v);
    hHi[n*64+lane] = (unsigned short)hv;
    hLo[n*64+lane] = (unsigned short)f2bf(v - bf2f(hv));
    sv[2*w+q][lane] = v;
  }
  __syncthreads();
  #pragma unroll
  for (int q = 0; q < 2; ++q){
    int n = n0 + q;
    float acc = 0.f;
    #pragma unroll 8
    for (int i = 0; i < 64; ++i) acc = fmaf(sv[2*w+q][i], b1c[i*64+lane], acc);
    hb[n*64+lane] = acc;
    m[n*64+lane] = 0.f;
  }
}

// weight preprocessing: transposes + bf16 builds + LSTM quadrant-packs + zeros
__global__ void k_prep(const float* __restrict__ gwih, const float* __restrict__ gwhh,
                       const float* __restrict__ linw, const float* __restrict__ w1b,
                       const float* __restrict__ wih0, const float* __restrict__ whh0,
                       const float* __restrict__ wih1, const float* __restrict__ whh1,
                       const float* __restrict__ w2a,  const float* __restrict__ w1c,
                       float* __restrict__ wihT, float* __restrict__ whhT,
                       float* __restrict__ linT, unsigned short* __restrict__ w1bB,
                       float* __restrict__ p0i, float* __restrict__ p0h,
                       float* __restrict__ p1i, float* __restrict__ p1h,
                       float* __restrict__ w2aT, unsigned short* __restrict__ qtT,
                       int* __restrict__ deg, float* __restrict__ state0){
  int tid = blockIdx.x*256 + threadIdx.x;
  if (tid < 12288){ int i=tid>>6, j=tid&63; wihT[j*192+i]=gwih[tid]; return; }
  tid -= 12288;
  if (tid < 12288){ int i=tid>>6, j=tid&63; whhT[j*192+i]=gwhh[tid]; return; }
  tid -= 12288;
  if (tid < 9600){ int i=tid/75, j=tid-i*75; linT[j*128+i]=linw[tid]; return; }
  tid -= 9600;
  if (tid < 4096){ w1bB[tid] = (unsigned short)f2bf(w1b[tid]); return; }
  tid -= 4096;
  if (tid < 32768){ int i=tid>>7, j=tid&127;        // p0i[i][j] = 4 gate rows of wih0, col i
    float4 v = make_float4(wih0[(j)*256+i], wih0[(128+j)*256+i],
                           wih0[(256+j)*256+i], wih0[(384+j)*256+i]);
    *(float4*)&p0i[tid*4] = v; return; }
  tid -= 32768;
  if (tid < 16384){ int i=tid>>7, j=tid&127;
    float4 v = make_float4(whh0[(j)*128+i], whh0[(128+j)*128+i],
                           whh0[(256+j)*128+i], whh0[(384+j)*128+i]);
    *(float4*)&p0h[tid*4] = v; return; }
  tid -= 16384;
  if (tid < 16384){ int i=tid>>7, j=tid&127;
    float4 v = make_float4(wih1[(j)*128+i], wih1[(128+j)*128+i],
                           wih1[(256+j)*128+i], wih1[(384+j)*128+i]);
    *(float4*)&p1i[tid*4] = v; return; }
  tid -= 16384;
  if (tid < 16384){ int i=tid>>7, j=tid&127;
    float4 v = make_float4(whh1[(j)*128+i], whh1[(128+j)*128+i],
                           whh1[(256+j)*128+i], whh1[(384+j)*128+i]);
    *(float4*)&p1h[tid*4] = v; return; }
  tid -= 16384;
  if (tid < 131072){ int i=tid>>8, j=tid&255; w2aT[j*512+i]=w2a[tid]; return; }
  tid -= 131072;
  if (tid < 262144){ int ko=tid>>6, hh=tid&63; int k=ko>>6, o=ko&63;
                     qtT[tid] = (unsigned short)f2bf(w1c[(hh*64+o)*64+k]); return; }
  tid -= 262144;
  if (tid < NN){ deg[tid] = 0; return; }
  tid -= NN;
  if (tid < 262144) state0[tid] = 0.f;   // qstar+h0+c0+h1+c1+h0b+h1b (contiguous)
}

// edge MLP via MFMA: wave = 16 edges.
__global__ __launch_bounds__(256) void k_e1m(const float* __restrict__ ea,
                     const float* __restrict__ w1a, const float* __restrict__ b1a,
                     const unsigned short* __restrict__ w1bB, const float* __restrict__ b1b,
                     unsigned short* __restrict__ e1b){
  __shared__ unsigned short sHi[4][16][64], sLo[4][16][64];   // 16 KB
  int t = threadIdx.x, w = t>>6, l = t&63;
  int c = l & 15, g = l >> 4;
  int eb = blockIdx.x*64 + w*16;
  float wa0=w1a[l*4+0], wa1=w1a[l*4+1], wa2=w1a[l*4+2], wa3=w1a[l*4+3];
  float bb1 = b1a[l];
  char* hbase = (char*)&sHi[w][0][0];
  char* lbase = (char*)&sLo[w][0][0];
  #pragma unroll
  for (int r = 0; r < 16; ++r){
    int e = eb + r; if (e >= NE) e = NE-1;
    float4 a = *(const float4*)&ea[e*4];
    float h1 = fmaxf(bb1 + a.x*wa0 + a.y*wa1 + a.z*wa2 + a.w*wa3, 0.f);
    u32 hv = f2bf(h1);
    u32 lv = f2bf(h1 - bf2f(hv));
    int wb = (r*128 + l*2) ^ ((r & 7) << 4);   // row-XOR swizzle
    *(unsigned short*)(hbase + wb) = (unsigned short)hv;
    *(unsigned short*)(lbase + wb) = (unsigned short)lv;
  }
  __syncthreads();
  int xv = (c & 7) << 4;
  int rb0 = (c*128 + g*16) ^ xv;
  int rb1 = (c*128 + 64 + g*16) ^ xv;
  short8v aH0 = *(const short8v*)(hbase + rb0);
  short8v aH1 = *(const short8v*)(hbase + rb1);
  short8v aL0 = *(const short8v*)(lbase + rb0);
  short8v aL1 = *(const short8v*)(lbase + rb1);
  f32x4 acc[4];
  #pragma unroll
  for (int f = 0; f < 4; ++f){
    const short* wrow = (const short*)w1bB + (f*16 + c)*64 + g*8;
    short8v b0 = *(const short8v*)wrow;
    short8v b1 = *(const short8v*)(wrow + 32);
    acc[f] = f32x4{0.f,0.f,0.f,0.f};
    acc[f] = __builtin_amdgcn_mfma_f32_16x16x32_bf16(aH0, b0, acc[f], 0, 0, 0);
    acc[f] = __builtin_amdgcn_mfma_f32_16x16x32_bf16(aL0, b0, acc[f], 0, 0, 0);
    acc[f] = __builtin_amdgcn_mfma_f32_16x16x32_bf16(aH1, b1, acc[f], 0, 0, 0);
    acc[f] = __builtin_amdgcn_mfma_f32_16x16x32_bf16(aL1, b1, acc[f], 0, 0, 0);
  }
  #pragma unroll
  for (int f = 0; f < 4; ++f){
    float bb2 = b1b[f*16 + c];
    #pragma unroll
    for (int r = 0; r < 4; ++r){
      int e = eb + 4*g + r;                 // C/D: row = 4*(lane>>4)+reg
      if (e < NE)
        e1b[e*64 + f*16 + c] = (unsigned short)f2bf(fmaxf(acc[f][r] + bb2, 0.f));
    }
  }
}

// ---- CSR build (by src) ----
__global__ void k_deg(const int* __restrict__ ei, int* __restrict__ deg){
  int e = blockIdx.x*256 + threadIdx.x;
  if (e >= NE) return;
  atomicAdd(&deg[ei[e]], 1);
}

__global__ __launch_bounds__(256) void k_scan(const int* __restrict__ deg, int* __restrict__ rowptr,
                       int* __restrict__ cursor){
  __shared__ int part[256];
  int t = threadIdx.x;
  int base = t*40;
  int s = 0;
  for (int i = 0; i < 40; ++i){ int idx = base+i; if (idx < NN) s += deg[idx]; }
  part[t] = s;
  __syncthreads();
  for (int off = 1; off < 256; off <<= 1){
    int v = (t >= off) ? part[t-off] : 0;
    __syncthreads();
    part[t] += v;
    __syncthreads();
  }
  int run = (t == 0) ? 0 : part[t-1];
  for (int i = 0; i < 40; ++i){
    int idx = base+i;
    if (idx < NN){ rowptr[idx] = run; cursor[idx] = run; run += deg[idx]; }
  }
  if (t == 255) rowptr[NN] = part[255];
}

__global__ void k_fill(const int* __restrict__ ei, int* __restrict__ cursor, int* __restrict__ csr_e){
  int e = blockIdx.x*256 + threadIdx.x;
  if (e >= NE) return;
  int s = ei[e];
  int pos = atomicAdd(&cursor[s], 1);
  csr_e[pos] = e;
}

// FUSED P + message pass: block = 32 nodes, 512 threads (8 waves).
// Loops 16 ko-tiles: MFMA P fragment (32n x 4k x 64o) -> LDS, then per-edge
// accumulation (edge/wave, o/lane) into persistent registers. No P2 tensor.
__global__ __launch_bounds__(512) void k_fuse(
    const unsigned short* __restrict__ hHi, const unsigned short* __restrict__ hLo,
    const unsigned short* __restrict__ qtT, const unsigned short* __restrict__ e1b,
    const int* __restrict__ rowptr, const int* __restrict__ csr_e,
    const int* __restrict__ ei, const float* __restrict__ hb,
    float* __restrict__ m){
  __shared__ unsigned short sQ[16384];        // 32 KB qtT tile (swizzled)
  __shared__ unsigned short sHi[32*64];       // 4 KB (swizzled rows)
  __shared__ unsigned short sLo[32*64];       // 4 KB
  __shared__ u32 sP[32*128];                  // 16 KB P fragment (perm-o, k-paired)
  __shared__ unsigned short sE[256*64];       // 32 KB e1 rows (csr order)
  __shared__ unsigned char  sSrc[256];
  __shared__ unsigned short sDst[256];
  int t = threadIdx.x;
  int w = t >> 6, l = t & 63;
  int c = l & 15, g = l >> 4;
  int n0 = blockIdx.x * 32;
  int nEnd = n0 + 32; if (nEnd > NN) nEnd = NN;
  int jb = rowptr[n0], je = rowptr[nEnd];
  int E = je - jb; if (E > 256) E = 256;      // capacity guard (7.6 sigma)
  // stage sHi/sLo (row-XOR swizzled)
  {
    int idx = t & 255;
    int row = idx >> 3, q = idx & 7;
    int srcRow = n0 + row; if (srcRow >= NN) srcRow = NN - 1;
    int db = (row*128 + q*16) ^ ((row & 7) << 4);
    if (t < 256)
      *(uint4*)((char*)sHi + db) = *(const uint4*)((const char*)hHi + (size_t)srcRow*128 + q*16);
    else
      *(uint4*)((char*)sLo + db) = *(const uint4*)((const char*)hLo + (size_t)srcRow*128 + q*16);
  }
  // stage e1 rows (32 B quarters) + dst
  for (int idx = t; idx < E*4; idx += 512){
    int r = idx >> 2, q = idx & 3;
    int e = csr_e[jb + r];
    *(uint4*)((char*)sE + r*128 + q*32)      = *(const uint4*)((const char*)e1b + (size_t)e*128 + q*32);
    *(uint4*)((char*)sE + r*128 + q*32 + 16) = *(const uint4*)((const char*)e1b + (size_t)e*128 + q*32 + 16);
  }
  for (int p = t; p < E; p += 512)
    sDst[p] = (unsigned short)ei[NE + csr_e[jb + p]];
  if (t < 32){
    int n = n0 + t;
    if (n < NN){
      int a = rowptr[n] - jb, b = rowptr[n+1] - jb;
      if (b > 256) b = 256;
      for (int p = a; p < b; ++p) sSrc[p] = (unsigned char)t;
    }
  }
  __syncthreads();
  // per-wave role: wn = node-group (0/1), fq = frag quarter (0..3)
  int wn = w & 1, fq = w >> 1;
  int rowA = wn*16 + c;
  int swz = (rowA & 7) << 4;
  short8v aH0 = *(const short8v*)((char*)sHi + ((rowA*128 + g*16) ^ swz));
  short8v aH1 = *(const short8v*)((char*)sHi + ((rowA*128 + 64 + g*16) ^ swz));
  short8v aL0 = *(const short8v*)((char*)sLo + ((rowA*128 + g*16) ^ swz));
  short8v aL1 = *(const short8v*)((char*)sLo + ((rowA*128 + 64 + g*16) ^ swz));
  int ew = 0; if (E > w) ew = (E - w + 7) >> 3; if (ew > 32) ew = 32;
  float acc[32];
  #pragma unroll
  for (int i = 0; i < 32; ++i) acc[i] = 0.f;
  int xv = (c & 7) << 4;
  for (int T = 0; T < 16; ++T){
    // stage qtT tile (involution pre-swizzle, as k_P3)
    {
      const char* qsrc = (const char*)qtT + (size_t)T*32768;
      #pragma unroll
      for (int r = 0; r < 4; ++r){
        int dstb = (r*512 + t)*16;
        int srcb = dstb ^ (((dstb >> 7) & 7) << 4);
        *(uint4*)((char*)sQ + dstb) = *(const uint4*)(qsrc + srcb);
      }
    }
    __syncthreads();
    // MFMA: frags F = fq + 4*f  (o = fq*16+c, k-off = f)
    f32x4 a4[4];
    #pragma unroll
    for (int f = 0; f < 4; ++f){
      int F = fq + 4*f;
      int baseb = F*2048 + c*128 + g*16;
      short8v b0 = *(const short8v*)((char*)sQ + (baseb ^ xv));
      short8v b1 = *(const short8v*)((char*)sQ + ((baseb + 64) ^ xv));
      f32x4 a = f32x4{0.f,0.f,0.f,0.f};
      a = __builtin_amdgcn_mfma_f32_16x16x32_bf16(aH0, b0, a, 0, 0, 0);
      a = __builtin_amdgcn_mfma_f32_16x16x32_bf16(aL0, b0, a, 0, 0, 0);
      a = __builtin_amdgcn_mfma_f32_16x16x32_bf16(aH1, b1, a, 0, 0, 0);
      a = __builtin_amdgcn_mfma_f32_16x16x32_bf16(aL1, b1, a, 0, 0, 0);
      a4[f] = a;
    }
    // write P fragment: [node][kk(2)][c*4+fq] u32 = pack(k even, k odd)
    #pragma unroll
    for (int r = 0; r < 4; ++r){
      int node = wn*16 + 4*g + r;
      sP[node*128 + c*4 + fq]      = f2bf(a4[0][r]) | (f2bf(a4[1][r]) << 16);
      sP[node*128 + 64 + c*4 + fq] = f2bf(a4[2][r]) | (f2bf(a4[3][r]) << 16);
    }
    __syncthreads();
    // edge accumulate: wave w owns csr positions w + 8*i
    #pragma unroll
    for (int i = 0; i < 32; ++i){
      if (i < ew){
        int p = w + 8*i;
        int src = sSrc[p];
        u32 e01 = *(const u32*)((char*)sE + p*128 + T*8);
        u32 e23 = *(const u32*)((char*)sE + p*128 + T*8 + 4);
        u32 p01 = sP[src*128 + l];
        u32 p23 = sP[src*128 + 64 + l];
        float s = acc[i];
        s = fmaf(bf2f(e01 & 0xffffu), bf2f(p01 & 0xffffu), s);
        s = fmaf(bf2f(e01 >> 16),     bf2f(p01 >> 16),     s);
        s = fmaf(bf2f(e23 & 0xffffu), bf2f(p23 & 0xffffu), s);
        s = fmaf(bf2f(e23 >> 16),     bf2f(p23 >> 16),     s);
        acc[i] = s;
      }
    }
    __syncthreads();
  }
  // finalize: + hb[src], scatter to m[dst]
  int oo = ((l & 3) << 4) | (l >> 2);
  #pragma unroll
  for (int i = 0; i < 32; ++i){
    if (i < ew){
      int p = w + 8*i;
      int src = sSrc[p];
      int dst = sDst[p];
      float v = acc[i] + hb[(n0 + src)*64 + oo];
      atomicAdd(&m[dst*64 + oo], v);
    }
  }
}

// GRU: 2 nodes per wave; emits bf16 hi/lo of new h; epilogue computes
// hb = h_new @ b1c and zeroes m for the NEXT message pass.
__global__ __launch_bounds__(256) void k_gru(const float* __restrict__ m, float* __restrict__ h,
                     unsigned short* __restrict__ hHi, unsigned short* __restrict__ hLo,
                     const float* __restrict__ wihT, const float* __restrict__ whhT,
                     const float* __restrict__ bih, const float* __restrict__ bhh,
                     const float* __restrict__ b1c, float* __restrict__ hb,
                     float* __restrict__ mz){
  __shared__ float sm[8][64], sh[8][64], sv[8][64];
  int t = threadIdx.x, w = t>>6, lane = t&63;
  int n0 = blockIdx.x*8 + w*2;
  sm[2*w][lane]   = m[n0*64+lane];
  sm[2*w+1][lane] = m[(n0+1)*64+lane];
  sh[2*w][lane]   = h[n0*64+lane];
  sh[2*w+1][lane] = h[(n0+1)*64+lane];
  __syncthreads();
  float gi[2][3] = {{0,0,0},{0,0,0}}, gh[2][3] = {{0,0,0},{0,0,0}};
  #pragma unroll 2
  for (int i=0;i<64;++i){
    const float* wr = wihT + i*192;
    const float* ur = whhT + i*192;
    float w0=wr[lane], w1=wr[64+lane], w2=wr[128+lane];
    float u0=ur[lane], u1=ur[64+lane], u2=ur[128+lane];
    #pragma unroll
    for (int q=0;q<2;++q){
      float mi = sm[2*w+q][i], hi = sh[2*w+q][i];
      gi[q][0]=fmaf(mi,w0,gi[q][0]); gi[q][1]=fmaf(mi,w1,gi[q][1]); gi[q][2]=fmaf(mi,w2,gi[q][2]);
      gh[q][0]=fmaf(hi,u0,gh[q][0]); gh[q][1]=fmaf(hi,u1,gh[q][1]); gh[q][2]=fmaf(hi,u2,gh[q][2]);
    }
  }
  #pragma unroll
  for (int q=0;q<2;++q){
    int n = n0 + q;
    float r  = sigm(gi[q][0]+bih[lane]      + gh[q][0]+bhh[lane]);
    float z  = sigm(gi[q][1]+bih[64+lane]   + gh[q][1]+bhh[64+lane]);
    float nn_= tanhf(gi[q][2]+bih[128+lane] + r*(gh[q][2]+bhh[128+lane]));
    float ho = sh[2*w+q][lane];
    float hv = (1.f-z)*nn_ + z*ho;
    h[n*64+lane] = hv;
    u32 hv16 = f2bf(hv);
    hHi[n*64+lane] = (unsigned short)hv16;
    hLo[n*64+lane] = (unsigned short)f2bf(hv - bf2f(hv16));
    sv[2*w+q][lane] = hv;
  }
  __syncthreads();
  #pragma unroll
  for (int q=0;q<2;++q){
    int n = n0 + q;
    float acc = 0.f;
    #pragma unroll 8
    for (int i = 0; i < 64; ++i) acc = fmaf(sv[2*w+q][i], b1c[i*64+lane], acc);
    hb[n*64+lane] = acc;
    mz[n*64+lane] = 0.f;
  }
}

// h2 = cat(h, x) @ lin_w^T + lin_b
__global__ __launch_bounds__(256) void k_lin(const float* __restrict__ h, const float* __restrict__ x,
                     const float* __restrict__ linT, const float* __restrict__ lin_b, float* __restrict__ h2){
  __shared__ float sh[4][64];
  int t=threadIdx.x, w=t>>6, lane=t&63;
  int n = blockIdx.x*4 + w;
  sh[w][lane] = h[n*64+lane];
  __syncthreads();
  float a0 = lin_b[lane], a1 = lin_b[64+lane];
  #pragma unroll 4
  for (int i=0;i<64;++i){
    float v = sh[w][i];
    a0 = fmaf(v, linT[i*128+lane], a0);
    a1 = fmaf(v, linT[i*128+64+lane], a1);
  }
  #pragma unroll
  for (int i=0;i<11;++i){
    float v = x[n*NNF+i];
    a0 = fmaf(v, linT[(64+i)*128+lane], a0);
    a1 = fmaf(v, linT[(64+i)*128+64+lane], a1);
  }
  h2[n*128+lane] = a0;
  h2[n*128+64+lane] = a1;
}

// graph ranges via binary search on sorted batch
__global__ void k_bounds(const int* __restrict__ batch, int* __restrict__ gstart){
  int b = blockIdx.x*256 + threadIdx.x;
  if (b > BG) return;
  int lo=0, hi=NN;
  while (lo < hi){ int mid=(lo+hi)>>1; if (batch[mid] < b) lo=mid+1; else hi=mid; }
  gstart[b]=lo;
}

// LSTM layer 0, reduction-split: grid 512 = (graph-pair 128) x (unit-quarter 4).
__global__ __launch_bounds__(256) void k_lstmA(
    const float* __restrict__ qstar, const float* __restrict__ h0r,
    float* __restrict__ c0, float* __restrict__ h0w,
    const f32x4* __restrict__ p0i, const f32x4* __restrict__ p0h,
    const float* __restrict__ bih0, const float* __restrict__ bhh0){
  __shared__ float sq[512], sh[256];
  __shared__ float red[8][2][32][5];
  int t = threadIdx.x;
  int gp = blockIdx.x >> 2, uq = blockIdx.x & 3;
  int g0 = gp*2;
  int u = t & 31, c = t >> 5;
  int j = uq*32 + u;
  sq[t]       = qstar[(size_t)g0*256 + t];
  sq[t + 256] = qstar[(size_t)g0*256 + 256 + t];
  sh[t]       = h0r[g0*128 + t];
  __syncthreads();
  float ai=0,af=0,ag=0,ao=0, bi=0,bf_=0,bg=0,bo=0;
  #pragma unroll 8
  for (int k = 0; k < 32; ++k){
    int i = c*32 + k;
    f32x4 w = p0i[i*128 + j];
    float x0 = sq[i], x1 = sq[256+i];
    ai=fmaf(x0,w[0],ai); af=fmaf(x0,w[1],af); ag=fmaf(x0,w[2],ag); ao=fmaf(x0,w[3],ao);
    bi=fmaf(x1,w[0],bi); bf_=fmaf(x1,w[1],bf_); bg=fmaf(x1,w[2],bg); bo=fmaf(x1,w[3],bo);
  }
  #pragma unroll 8
  for (int k = 0; k < 16; ++k){
    int i = c*16 + k;
    f32x4 w = p0h[i*128 + j];
    float x0 = sh[i], x1 = sh[128+i];
    ai=fmaf(x0,w[0],ai); af=fmaf(x0,w[1],af); ag=fmaf(x0,w[2],ag); ao=fmaf(x0,w[3],ao);
    bi=fmaf(x1,w[0],bi); bf_=fmaf(x1,w[1],bf_); bg=fmaf(x1,w[2],bg); bo=fmaf(x1,w[3],bo);
  }
  red[c][0][u][0]=ai; red[c][0][u][1]=af; red[c][0][u][2]=ag; red[c][0][u][3]=ao;
  red[c][1][u][0]=bi; red[c][1][u][1]=bf_; red[c][1][u][2]=bg; red[c][1][u][3]=bo;
  __syncthreads();
  if (t < 64){
    int g = t >> 5, uu = t & 31;
    int jj = uq*32 + uu;
    float G[4];
    #pragma unroll
    for (int q = 0; q < 4; ++q){
      float s = bih0[q*128 + jj] + bhh0[q*128 + jj];
      #pragma unroll
      for (int cc = 0; cc < 8; ++cc) s += red[cc][g][uu][q];
      G[q] = s;
    }
    int idx = (g0 + g)*128 + jj;
    float cc0 = c0[idx];
    float ig = sigm(G[0]), fg = sigm(G[1]), gg = tanhf(G[2]), og = sigm(G[3]);
    float cn = fg*cc0 + ig*gg;
    c0[idx] = cn;
    h0w[idx] = og*tanhf(cn);
  }
}

// LSTM layer 1: same decomposition.
__global__ __launch_bounds__(256) void k_lstmB(
    const float* __restrict__ h0n, const float* __restrict__ h1r,
    float* __restrict__ c1, float* __restrict__ h1w, float* __restrict__ qstar,
    const f32x4* __restrict__ p1i, const f32x4* __restrict__ p1h,
    const float* __restrict__ bih1, const float* __restrict__ bhh1){
  __shared__ float s0[256], s1[256];
  __shared__ float red[8][2][32][5];
  int t = threadIdx.x;
  int gp = blockIdx.x >> 2, uq = blockIdx.x & 3;
  int g0 = gp*2;
  int u = t & 31, c = t >> 5;
  int j = uq*32 + u;
  s0[t] = h0n[g0*128 + t];
  s1[t] = h1r[g0*128 + t];
  __syncthreads();
  float ai=0,af=0,ag=0,ao=0, bi=0,bf_=0,bg=0,bo=0;
  #pragma unroll 8
  for (int k = 0; k < 16; ++k){
    int i = c*16 + k;
    f32x4 w = p1i[i*128 + j];
    float x0 = s0[i], x1 = s0[128+i];
    ai=fmaf(x0,w[0],ai); af=fmaf(x0,w[1],af); ag=fmaf(x0,w[2],ag); ao=fmaf(x0,w[3],ao);
    bi=fmaf(x1,w[0],bi); bf_=fmaf(x1,w[1],bf_); bg=fmaf(x1,w[2],bg); bo=fmaf(x1,w[3],bo);
  }
  #pragma unroll 8
  for (int k = 0; k < 16; ++k){
    int i = c*16 + k;
    f32x4 w = p1h[i*128 + j];
    float x0 = s1[i], x1 = s1[128+i];
    ai=fmaf(x0,w[0],ai); af=fmaf(x0,w[1],af); ag=fmaf(x0,w[2],ag); ao=fmaf(x0,w[3],ao);
    bi=fmaf(x1,w[0],bi); bf_=fmaf(x1,w[1],bf_); bg=fmaf(x1,w[2],bg); bo=fmaf(x1,w[3],bo);
  }
  red[c][0][u][0]=ai; red[c][0][u][1]=af; red[c][0][u][2]=ag; red[c][0][u][3]=ao;
  red[c][1][u][0]=bi; red[c][1][u][1]=bf_; red[c][1][u][2]=bg; red[c][1][u][3]=bo;
  __syncthreads();
  if (t < 64){
    int g = t >> 5, uu = t & 31;
    int jj = uq*32 + uu;
    float G[4];
    #pragma unroll
    for (int q = 0; q < 4; ++q){
      float s = bih1[q*128 + jj] + bhh1[q*128 + jj];
      #pragma unroll
      for (int cc = 0; cc < 8; ++cc) s += red[cc][g][uu][q];
      G[q] = s;
    }
    int idx = (g0 + g)*128 + jj;
    float cc1 = c1[idx];
    float ig = sigm(G[0]), fg = sigm(G[1]), gg = tanhf(G[2]), og = sigm(G[3]);
    float cn = fg*cc1 + ig*gg;
    c1[idx] = cn;
    float hn = og*tanhf(cn);
    h1w[idx] = hn;
    qstar[(size_t)(g0 + g)*256 + jj] = hn;   // q part of q_star
  }
}

// attention readout: block = one graph, 4 waves stride the node range
__global__ __launch_bounds__(256) void k_attn2(const float* __restrict__ h2,
                       const float* __restrict__ h1,
                       const int* __restrict__ gstart, float* __restrict__ qstar){
  __shared__ float pm[4], pl[4], pr[4][128];
  int b = blockIdx.x, t = threadIdx.x, w = t>>6, lane = t&63;
  float q0 = h1[b*128+lane], q1 = h1[b*128+64+lane];
  int s = gstart[b], e = gstart[b+1];
  float mrun = -3.0e38f, l = 0.f, r0 = 0.f, r1 = 0.f;
  for (int n = s + w; n < e; n += 4){
    float v0 = h2[n*128+lane], v1 = h2[n*128+64+lane];
    float d = fmaf(v0, q0, v1*q1);
    #pragma unroll
    for (int off = 32; off; off >>= 1) d += __shfl_xor(d, off);
    float mn = fmaxf(mrun, d);
    float sc = __expf(mrun - mn);
    float ww = __expf(d - mn);
    l = l*sc + ww;
    r0 = r0*sc + ww*v0;
    r1 = r1*sc + ww*v1;
    mrun = mn;
  }
  pr[w][lane] = r0; pr[w][64+lane] = r1;
  if (lane == 0){ pm[w] = mrun; pl[w] = l; }
  __syncthreads();
  if (t < 128){
    float M = fmaxf(fmaxf(pm[0],pm[1]), fmaxf(pm[2],pm[3]));
    float L = 0.f, R = 0.f;
    #pragma unroll
    for (int ww = 0; ww < 4; ++ww){
      float sc = __expf(pm[ww] - M);
      L = fmaf(pl[ww], sc, L);
      R = fmaf(pr[ww][t], sc, R);
    }
    float inv = (L > 0.f) ? 1.f/L : 0.f;
    qstar[b*256 + 128 + t] = R*inv;
  }
}

// head: mid = relu(qstar @ w2aT + b2a); out = mid @ w2b^T + b2b. block = graph.
__global__ __launch_bounds__(512) void k_head(const float* __restrict__ qstar,
                      const float* __restrict__ w2aT, const float* __restrict__ b2a,
                      const float* __restrict__ w2b,  const float* __restrict__ b2b,
                      float* __restrict__ out){
  __shared__ float qs[256], sg[512];
  int b = blockIdx.x, j = threadIdx.x, w = j>>6, lane = j&63;
  if (j < 256) qs[j] = qstar[b*256 + j];
  __syncthreads();
  float a0 = b2a[j], a1 = 0.f, a2 = 0.f, a3 = 0.f;
  #pragma unroll
  for (int i = 0; i < 256; i += 4){
    a0 = fmaf(qs[i],   w2aT[(i)*512+j],   a0);
    a1 = fmaf(qs[i+1], w2aT[(i+1)*512+j], a1);
    a2 = fmaf(qs[i+2], w2aT[(i+2)*512+j], a2);
    a3 = fmaf(qs[i+3], w2aT[(i+3)*512+j], a3);
  }
  sg[j] = fmaxf((a0+a1)+(a2+a3), 0.f);
  __syncthreads();
  for (int jj = w; jj < NT; jj += 8){
    const float* wr = w2b + jj*512;
    float acc = 0.f;
    #pragma unroll
    for (int i = 0; i < 8; ++i) acc = fmaf(sg[lane+i*64], wr[lane+i*64], acc);
    #pragma unroll
    for (int off = 32; off; off >>= 1) acc += __shfl_xor(acc, off);
    if (lane == 0) out[b*NT+jj] = acc + b2b[jj];
  }
}

extern "C" void kernel_launch(void* const* d_in, const int* in_sizes, int n_in,
                              void* d_out, int out_size, void* d_ws, size_t ws_size,
                              hipStream_t stream) {
  const float* x    = (const float*)d_in[0];
  const float* ea   = (const float*)d_in[1];
  const int*   eidx = (const int*)d_in[2];
  const int*   batch= (const int*)d_in[3];
  const float* w1a  = (const float*)d_in[5];
  const float* b1a  = (const float*)d_in[6];
  const float* w1b  = (const float*)d_in[7];
  const float* b1b  = (const float*)d_in[8];
  const float* w1c  = (const float*)d_in[9];
  const float* b1c  = (const float*)d_in[10];
  const float* gwih = (const float*)d_in[11];
  const float* gwhh = (const float*)d_in[12];
  const float* gbih = (const float*)d_in[13];
  const float* gbhh = (const float*)d_in[14];
  const float* linw = (const float*)d_in[15];
  const float* linb = (const float*)d_in[16];
  const float* wih0 = (const float*)d_in[17];
  const float* whh0 = (const float*)d_in[18];
  const float* bih0 = (const float*)d_in[19];
  const float* bhh0 = (const float*)d_in[20];
  const float* wih1 = (const float*)d_in[21];
  const float* whh1 = (const float*)d_in[22];
  const float* bih1 = (const float*)d_in[23];
  const float* bhh1 = (const float*)d_in[24];
  const float* w2a  = (const float*)d_in[25];
  const float* b2a  = (const float*)d_in[26];
  const float* w2b  = (const float*)d_in[27];
  const float* b2b  = (const float*)d_in[28];
  float* out = (float*)d_out;

  char* p = (char*)d_ws;
  auto alloc = [&](size_t nbytes){ void* r = (void*)p; p += (nbytes + 255) & ~size_t(255); return r; };
  float* h    = (float*)alloc((size_t)NN*64*4);
  float* hb   = (float*)alloc((size_t)NN*64*4);
  float* m    = (float*)alloc((size_t)NN*64*4);
  float* h2   = (float*)alloc((size_t)NN*128*4);
  float* wihT = (float*)alloc(64*192*4);
  float* whhT = (float*)alloc(64*192*4);
  float* linT = (float*)alloc(75*128*4);
  unsigned short* w1bB = (unsigned short*)alloc(64*64*2);
  float* p0i  = (float*)alloc(131072*4);
  float* p0h  = (float*)alloc(65536*4);
  float* p1i  = (float*)alloc(65536*4);
  float* p1h  = (float*)alloc(65536*4);
  float* w2aT = (float*)alloc(256*512*4);
  // state block: qstar + h0 + c0 + h1 + c1 + h0b + h1b, contiguous zero-init
  float* qstar= (float*)alloc(256*256*4);
  float* h0   = (float*)alloc(256*128*4);
  float* c0   = (float*)alloc(256*128*4);
  float* h1s  = (float*)alloc(256*128*4);
  float* c1   = (float*)alloc(256*128*4);
  float* h0b2 = (float*)alloc(256*128*4);
  float* h1b2 = (float*)alloc(256*128*4);
  int*  gstart= (int*)alloc(257*4);
  unsigned short* e1b = (unsigned short*)alloc((size_t)NE*64*2);
  unsigned short* qtT = (unsigned short*)alloc((size_t)4096*64*2);
  unsigned short* hHi = (unsigned short*)alloc((size_t)NN*64*2);
  unsigned short* hLo = (unsigned short*)alloc((size_t)NN*64*2);
  int*  deg   = (int*)alloc((size_t)NN*4);
  int*  rowptr= (int*)alloc((size_t)(NN+1)*4);
  int*  cursor= (int*)alloc((size_t)NN*4);
  int*  csr_e = (int*)alloc((size_t)NE*4);

  k_prep<<<3069, 256, 0, stream>>>(gwih, gwhh, linw, w1b, wih0, whh0, wih1, whh1,
                                   w2a, w1c, wihT, whhT, linT, w1bB, p0i, p0h,
                                   p1i, p1h, w2aT, qtT, deg, qstar);
  k_h_init<<<1250, 256, 0, stream>>>(x, h, hHi, hLo, b1c, hb, m);
  k_e1m<<<782, 256, 0, stream>>>(ea, w1a, b1a, w1bB, b1b, e1b);
  k_bounds<<<2, 256, 0, stream>>>(batch, gstart);
  k_deg<<<196, 256, 0, stream>>>(eidx, deg);
  k_scan<<<1, 256, 0, stream>>>(deg, rowptr, cursor);
  k_fill<<<196, 256, 0, stream>>>(eidx, cursor, csr_e);

  for (int t = 0; t < 3; ++t) {
    k_fuse<<<313, 512, 0, stream>>>(hHi, hLo, qtT, e1b, rowptr, csr_e, eidx, hb, m);
    k_gru<<<1250, 256, 0, stream>>>(m, h, hHi, hLo, wihT, whhT, gbih, gbhh, b1c, hb, m);
  }

  k_lin<<<2500, 256, 0, stream>>>(h, x, linT, linb, h2);

  for (int s = 0; s < 3; ++s) {
    float* h0r = (s & 1) ? h0b2 : h0;
    float* h0w = (s & 1) ? h0   : h0b2;
    float* h1r = (s & 1) ? h1b2 : h1s;
    float* h1w = (s & 1) ? h1s  : h1b2;
    k_lstmA<<<512, 256, 0, stream>>>(qstar, h0r, c0, h0w, (const f32x4*)p0i,
                                     (const f32x4*)p0h, bih0, bhh0);
    k_lstmB<<<512, 256, 0, stream>>>(h0w, h1r, c1, h1w, qstar, (const f32x4*)p1i,
                                     (const f32x4*)p1h, bih1, bhh1);
    k_attn2<<<256, 256, 0, stream>>>(h2, h1w, gstart, qstar);
  }

  k_head<<<256, 512, 0, stream>>>(qstar, w2aT, b2a, w2b, b2b, out);
}

// Round 13
// 484.916 us; speedup vs baseline: 1.4010x; 1.4010x over previous
//
#include <hip/hip_runtime.h>
#include <math.h>

#define NN 10000
#define NE 50000
#define BG 256
#define NNF 11
#define NT 12

typedef unsigned int u32;
typedef __attribute__((ext_vector_type(8))) short short8v;   // 8 bf16 (4 VGPRs)
typedef __attribute__((ext_vector_type(4))) float f32x4;

__device__ __forceinline__ float sigm(float x){ return 1.0f/(1.0f+__expf(-x)); }
__device__ __forceinline__ u32 f2bf(float f){
  u32 u = __float_as_uint(f);
  return (u + 0x7fffu + ((u>>16)&1u)) >> 16;   // RNE
}
__device__ __forceinline__ float bf2f(u32 s){ return __uint_as_float(s<<16); }

// wave-per-node init: h from x, bf16 hi/lo split, hb = h@b1c, m = 0.
__global__ __launch_bounds__(256) void k_h_init(const float* __restrict__ x, float* __restrict__ h,
                         unsigned short* __restrict__ hHi, unsigned short* __restrict__ hLo,
                         const float* __restrict__ b1c, float* __restrict__ hb,
                         float* __restrict__ m){
  __shared__ float sv[8][64];
  int t = threadIdx.x, w = t>>6, lane = t&63;
  int n0 = blockIdx.x*8 + w*2;
  #pragma unroll
  for (int q = 0; q < 2; ++q){
    int n = n0 + q;
    float v = (lane < NNF) ? x[n*NNF + lane] : 0.0f;
    h[n*64+lane] = v;
    u32 hv = f2bf(v);
    hHi[n*64+lane] = (unsigned short)hv;
    hLo[n*64+lane] = (unsigned short)f2bf(v - bf2f(hv));
    sv[2*w+q][lane] = v;
  }
  __syncthreads();
  #pragma unroll
  for (int q = 0; q < 2; ++q){
    int n = n0 + q;
    float acc = 0.f;
    #pragma unroll 8
    for (int i = 0; i < 64; ++i) acc = fmaf(sv[2*w+q][i], b1c[i*64+lane], acc);
    hb[n*64+lane] = acc;
    m[n*64+lane] = 0.f;
  }
}

// weight preprocessing: transposes + bf16 builds + LSTM quadrant-packs + zeros
__global__ void k_prep(const float* __restrict__ gwih, const float* __restrict__ gwhh,
                       const float* __restrict__ linw, const float* __restrict__ w1b,
                       const float* __restrict__ wih0, const float* __restrict__ whh0,
                       const float* __restrict__ wih1, const float* __restrict__ whh1,
                       const float* __restrict__ w2a,  const float* __restrict__ w1c,
                       float* __restrict__ wihT, float* __restrict__ whhT,
                       float* __restrict__ linT, unsigned short* __restrict__ w1bB,
                       float* __restrict__ p0i, float* __restrict__ p0h,
                       float* __restrict__ p1i, float* __restrict__ p1h,
                       float* __restrict__ w2aT, unsigned short* __restrict__ qtT,
                       int* __restrict__ deg, float* __restrict__ state0){
  int tid = blockIdx.x*256 + threadIdx.x;
  if (tid < 12288){ int i=tid>>6, j=tid&63; wihT[j*192+i]=gwih[tid]; return; }
  tid -= 12288;
  if (tid < 12288){ int i=tid>>6, j=tid&63; whhT[j*192+i]=gwhh[tid]; return; }
  tid -= 12288;
  if (tid < 9600){ int i=tid/75, j=tid-i*75; linT[j*128+i]=linw[tid]; return; }
  tid -= 9600;
  if (tid < 4096){ w1bB[tid] = (unsigned short)f2bf(w1b[tid]); return; }
  tid -= 4096;
  if (tid < 32768){ int i=tid>>7, j=tid&127;        // p0i[i][j] = 4 gate rows of wih0, col i
    float4 v = make_float4(wih0[(j)*256+i], wih0[(128+j)*256+i],
                           wih0[(256+j)*256+i], wih0[(384+j)*256+i]);
    *(float4*)&p0i[tid*4] = v; return; }
  tid -= 32768;
  if (tid < 16384){ int i=tid>>7, j=tid&127;
    float4 v = make_float4(whh0[(j)*128+i], whh0[(128+j)*128+i],
                           whh0[(256+j)*128+i], whh0[(384+j)*128+i]);
    *(float4*)&p0h[tid*4] = v; return; }
  tid -= 16384;
  if (tid < 16384){ int i=tid>>7, j=tid&127;
    float4 v = make_float4(wih1[(j)*128+i], wih1[(128+j)*128+i],
                           wih1[(256+j)*128+i], wih1[(384+j)*128+i]);
    *(float4*)&p1i[tid*4] = v; return; }
  tid -= 16384;
  if (tid < 16384){ int i=tid>>7, j=tid&127;
    float4 v = make_float4(whh1[(j)*128+i], whh1[(128+j)*128+i],
                           whh1[(256+j)*128+i], whh1[(384+j)*128+i]);
    *(float4*)&p1h[tid*4] = v; return; }
  tid -= 16384;
  if (tid < 131072){ int i=tid>>8, j=tid&255; w2aT[j*512+i]=w2a[tid]; return; }
  tid -= 131072;
  if (tid < 262144){ int ko=tid>>6, hh=tid&63; int k=ko>>6, o=ko&63;
                     qtT[tid] = (unsigned short)f2bf(w1c[(hh*64+o)*64+k]); return; }
  tid -= 262144;
  if (tid < NN){ deg[tid] = 0; return; }
  tid -= NN;
  if (tid < 262144) state0[tid] = 0.f;   // qstar+h0+c0+h1+c1+h0b+h1b (contiguous)
}

// edge MLP via MFMA: wave = 16 edges.
__global__ __launch_bounds__(256) void k_e1m(const float* __restrict__ ea,
                     const float* __restrict__ w1a, const float* __restrict__ b1a,
                     const unsigned short* __restrict__ w1bB, const float* __restrict__ b1b,
                     unsigned short* __restrict__ e1b){
  __shared__ unsigned short sHi[4][16][64], sLo[4][16][64];   // 16 KB
  int t = threadIdx.x, w = t>>6, l = t&63;
  int c = l & 15, g = l >> 4;
  int eb = blockIdx.x*64 + w*16;
  float wa0=w1a[l*4+0], wa1=w1a[l*4+1], wa2=w1a[l*4+2], wa3=w1a[l*4+3];
  float bb1 = b1a[l];
  char* hbase = (char*)&sHi[w][0][0];
  char* lbase = (char*)&sLo[w][0][0];
  #pragma unroll
  for (int r = 0; r < 16; ++r){
    int e = eb + r; if (e >= NE) e = NE-1;
    float4 a = *(const float4*)&ea[e*4];
    float h1 = fmaxf(bb1 + a.x*wa0 + a.y*wa1 + a.z*wa2 + a.w*wa3, 0.f);
    u32 hv = f2bf(h1);
    u32 lv = f2bf(h1 - bf2f(hv));
    int wb = (r*128 + l*2) ^ ((r & 7) << 4);   // row-XOR swizzle
    *(unsigned short*)(hbase + wb) = (unsigned short)hv;
    *(unsigned short*)(lbase + wb) = (unsigned short)lv;
  }
  __syncthreads();
  int xv = (c & 7) << 4;
  int rb0 = (c*128 + g*16) ^ xv;
  int rb1 = (c*128 + 64 + g*16) ^ xv;
  short8v aH0 = *(const short8v*)(hbase + rb0);
  short8v aH1 = *(const short8v*)(hbase + rb1);
  short8v aL0 = *(const short8v*)(lbase + rb0);
  short8v aL1 = *(const short8v*)(lbase + rb1);
  f32x4 acc[4];
  #pragma unroll
  for (int f = 0; f < 4; ++f){
    const short* wrow = (const short*)w1bB + (f*16 + c)*64 + g*8;
    short8v b0 = *(const short8v*)wrow;
    short8v b1 = *(const short8v*)(wrow + 32);
    acc[f] = f32x4{0.f,0.f,0.f,0.f};
    acc[f] = __builtin_amdgcn_mfma_f32_16x16x32_bf16(aH0, b0, acc[f], 0, 0, 0);
    acc[f] = __builtin_amdgcn_mfma_f32_16x16x32_bf16(aL0, b0, acc[f], 0, 0, 0);
    acc[f] = __builtin_amdgcn_mfma_f32_16x16x32_bf16(aH1, b1, acc[f], 0, 0, 0);
    acc[f] = __builtin_amdgcn_mfma_f32_16x16x32_bf16(aL1, b1, acc[f], 0, 0, 0);
  }
  #pragma unroll
  for (int f = 0; f < 4; ++f){
    float bb2 = b1b[f*16 + c];
    #pragma unroll
    for (int r = 0; r < 4; ++r){
      int e = eb + 4*g + r;                 // C/D: row = 4*(lane>>4)+reg
      if (e < NE)
        e1b[e*64 + f*16 + c] = (unsigned short)f2bf(fmaxf(acc[f][r] + bb2, 0.f));
    }
  }
}

// P3: 512 threads = 8 waves; LDS-staged swizzled qtT tile shared by all waves.
__global__ __launch_bounds__(512) void k_P3(const unsigned short* __restrict__ hHi,
                      const unsigned short* __restrict__ hLo,
                      const unsigned short* __restrict__ qtT, u32* __restrict__ P2){
  __shared__ unsigned short sB[16384];     // 32 KB: [256 ko][64 hh] swizzled
  int t = threadIdx.x; int w = t >> 6; int l = t & 63;
  int c = l & 15, g = l >> 4;
  int nt = blockIdx.x >> 4, kt = blockIdx.x & 15;
  int kob = kt*256;
  const char* qsrc = (const char*)qtT + (size_t)kob*128;
  char* sb = (char*)sB;
  #pragma unroll
  for (int r = 0; r < 4; ++r){
    int dstb = (r*512 + t)*16;
    int srcb = dstb ^ (((dstb >> 7) & 7) << 4);    // involution pre-swizzle
    *(uint4*)(sb + dstb) = *(const uint4*)(qsrc + srcb);
  }
  int nb = nt*128 + w*16;
  int rowA = nb + c; if (rowA >= NN) rowA = NN-1;
  const short8v* aHiP = (const short8v*)((const short*)hHi + rowA*64 + g*8);
  const short8v* aLoP = (const short8v*)((const short*)hLo + rowA*64 + g*8);
  short8v aH0 = aHiP[0], aH1 = aHiP[4];
  short8v aL0 = aLoP[0], aL1 = aLoP[4];
  __syncthreads();
  int xv = (c & 7) << 4;
  f32x4 acc[16];
  #pragma unroll
  for (int f = 0; f < 16; ++f) acc[f] = f32x4{0.f,0.f,0.f,0.f};
  #pragma unroll
  for (int f = 0; f < 16; ++f){
    int baseb = f*2048 + c*128 + g*16;
    short8v b0 = *(const short8v*)(sb + (baseb ^ xv));
    short8v b1 = *(const short8v*)(sb + ((baseb + 64) ^ xv));
    acc[f] = __builtin_amdgcn_mfma_f32_16x16x32_bf16(aH0, b0, acc[f], 0, 0, 0);
    acc[f] = __builtin_amdgcn_mfma_f32_16x16x32_bf16(aL0, b0, acc[f], 0, 0, 0);
    acc[f] = __builtin_amdgcn_mfma_f32_16x16x32_bf16(aH1, b1, acc[f], 0, 0, 0);
    acc[f] = __builtin_amdgcn_mfma_f32_16x16x32_bf16(aL1, b1, acc[f], 0, 0, 0);
  }
  int k2b = kt*2;
  #pragma unroll
  for (int r = 0; r < 4; ++r){
    int node = nb + 4*g + r;
    if (node < NN){
      u32* dst = P2 + (size_t)node*2048;
      #pragma unroll
      for (int kk = 0; kk < 2; ++kk){
        uint4 v;
        v.x = f2bf(acc[8*kk+0][r]) | (f2bf(acc[8*kk+4][r]) << 16);
        v.y = f2bf(acc[8*kk+1][r]) | (f2bf(acc[8*kk+5][r]) << 16);
        v.z = f2bf(acc[8*kk+2][r]) | (f2bf(acc[8*kk+6][r]) << 16);
        v.w = f2bf(acc[8*kk+3][r]) | (f2bf(acc[8*kk+7][r]) << 16);
        *(uint4*)(dst + (k2b+kk)*64 + c*4) = v;
      }
    }
  }
}

// ---- CSR build (by src) ----
__global__ void k_deg(const int* __restrict__ ei, int* __restrict__ deg){
  int e = blockIdx.x*256 + threadIdx.x;
  if (e >= NE) return;
  atomicAdd(&deg[ei[e]], 1);
}

__global__ __launch_bounds__(256) void k_scan(const int* __restrict__ deg, int* __restrict__ rowptr,
                       int* __restrict__ cursor){
  __shared__ int part[256];
  int t = threadIdx.x;
  int base = t*40;
  int s = 0;
  for (int i = 0; i < 40; ++i){ int idx = base+i; if (idx < NN) s += deg[idx]; }
  part[t] = s;
  __syncthreads();
  for (int off = 1; off < 256; off <<= 1){
    int v = (t >= off) ? part[t-off] : 0;
    __syncthreads();
    part[t] += v;
    __syncthreads();
  }
  int run = (t == 0) ? 0 : part[t-1];
  for (int i = 0; i < 40; ++i){
    int idx = base+i;
    if (idx < NN){ rowptr[idx] = run; cursor[idx] = run; run += deg[idx]; }
  }
  if (t == 255) rowptr[NN] = part[255];
}

__global__ void k_fill(const int* __restrict__ ei, int* __restrict__ cursor, int* __restrict__ csr_e){
  int e = blockIdx.x*256 + threadIdx.x;
  if (e >= NE) return;
  int s = ei[e];
  int pos = atomicAdd(&cursor[s], 1);
  csr_e[pos] = e;
}

// message pass, CSR by src: one wave per node; register-resident P row + prefetch.
__global__ __launch_bounds__(256, 2) void k_msg3(const int* __restrict__ rowptr,
                       const int* __restrict__ csr_e,
                       const int* __restrict__ ei, const u32* __restrict__ e1u,
                       const u32* __restrict__ P2, const float* __restrict__ hb,
                       float* __restrict__ m){
  int t = threadIdx.x; int w = t >> 6; int l = t & 63;
  int oo = ((l & 3) << 4) | (l >> 2);       // un-permute: lane l holds output dim oo
  int n = blockIdx.x*4 + w;
  int jb = rowptr[n], je = rowptr[n+1];
  if (jb == je) return;
  float hbv = hb[n*64 + oo];
  const u32* Pn = P2 + (size_t)n*2048;
  u32 pr[32];
  #pragma unroll
  for (int k2 = 0; k2 < 32; ++k2) pr[k2] = Pn[k2*64 + l];
  int e = csr_e[jb];
  uint4 q[8];
  {
    const uint4* er4 = (const uint4*)(e1u + (size_t)e*32);
    #pragma unroll
    for (int i = 0; i < 8; ++i) q[i] = er4[i];
  }
  for (int j = jb; j < je; ++j){
    int dst = ei[NE + e];
    int en = (j+1 < je) ? csr_e[j+1] : e;
    uint4 qn[8];
    const uint4* ern = (const uint4*)(e1u + (size_t)en*32);
    #pragma unroll
    for (int i = 0; i < 8; ++i) qn[i] = ern[i];
    float a0 = hbv, a1 = 0.f, a2 = 0.f, a3 = 0.f;
    #pragma unroll
    for (int i = 0; i < 8; ++i){
      u32 w0 = q[i].x, w1 = q[i].y, w2 = q[i].z, w3 = q[i].w;
      u32 p0 = pr[4*i], p1 = pr[4*i+1], p2 = pr[4*i+2], p3 = pr[4*i+3];
      a0 = fmaf(bf2f(w0 & 0xffffu), bf2f(p0 & 0xffffu), a0);
      a0 = fmaf(bf2f(w0 >> 16),     bf2f(p0 >> 16),     a0);
      a1 = fmaf(bf2f(w1 & 0xffffu), bf2f(p1 & 0xffffu), a1);
      a1 = fmaf(bf2f(w1 >> 16),     bf2f(p1 >> 16),     a1);
      a2 = fmaf(bf2f(w2 & 0xffffu), bf2f(p2 & 0xffffu), a2);
      a2 = fmaf(bf2f(w2 >> 16),     bf2f(p2 >> 16),     a2);
      a3 = fmaf(bf2f(w3 & 0xffffu), bf2f(p3 & 0xffffu), a3);
      a3 = fmaf(bf2f(w3 >> 16),     bf2f(p3 >> 16),     a3);
    }
    atomicAdd(&m[dst*64 + oo], (a0+a1)+(a2+a3));
    #pragma unroll
    for (int i = 0; i < 8; ++i) q[i] = qn[i];
    e = en;
  }
}

// GRU: 2 nodes per wave; emits bf16 hi/lo of new h; epilogue computes either
// hb = h_new @ b1c + m = 0 (for next message pass) or, on the LAST iteration,
// h2 = cat(h_new, x) @ lin_w^T + lin_b (k_lin fused in; hb/m skipped).
__global__ __launch_bounds__(256) void k_gru(const float* __restrict__ m, float* __restrict__ h,
                     unsigned short* __restrict__ hHi, unsigned short* __restrict__ hLo,
                     const float* __restrict__ wihT, const float* __restrict__ whhT,
                     const float* __restrict__ bih, const float* __restrict__ bhh,
                     const float* __restrict__ b1c, float* __restrict__ hb,
                     float* __restrict__ mz,
                     const float* __restrict__ x, const float* __restrict__ linT,
                     const float* __restrict__ lin_b, float* __restrict__ h2, int last){
  __shared__ float sm[8][64], sh[8][64], sv[8][64];
  int t = threadIdx.x, w = t>>6, lane = t&63;
  int n0 = blockIdx.x*8 + w*2;
  sm[2*w][lane]   = m[n0*64+lane];
  sm[2*w+1][lane] = m[(n0+1)*64+lane];
  sh[2*w][lane]   = h[n0*64+lane];
  sh[2*w+1][lane] = h[(n0+1)*64+lane];
  __syncthreads();
  float gi[2][3] = {{0,0,0},{0,0,0}}, gh[2][3] = {{0,0,0},{0,0,0}};
  #pragma unroll 2
  for (int i=0;i<64;++i){
    const float* wr = wihT + i*192;
    const float* ur = whhT + i*192;
    float w0=wr[lane], w1=wr[64+lane], w2=wr[128+lane];
    float u0=ur[lane], u1=ur[64+lane], u2=ur[128+lane];
    #pragma unroll
    for (int q=0;q<2;++q){
      float mi = sm[2*w+q][i], hi = sh[2*w+q][i];
      gi[q][0]=fmaf(mi,w0,gi[q][0]); gi[q][1]=fmaf(mi,w1,gi[q][1]); gi[q][2]=fmaf(mi,w2,gi[q][2]);
      gh[q][0]=fmaf(hi,u0,gh[q][0]); gh[q][1]=fmaf(hi,u1,gh[q][1]); gh[q][2]=fmaf(hi,u2,gh[q][2]);
    }
  }
  #pragma unroll
  for (int q=0;q<2;++q){
    int n = n0 + q;
    float r  = sigm(gi[q][0]+bih[lane]      + gh[q][0]+bhh[lane]);
    float z  = sigm(gi[q][1]+bih[64+lane]   + gh[q][1]+bhh[64+lane]);
    float nn_= tanhf(gi[q][2]+bih[128+lane] + r*(gh[q][2]+bhh[128+lane]));
    float ho = sh[2*w+q][lane];
    float hv = (1.f-z)*nn_ + z*ho;
    h[n*64+lane] = hv;
    u32 hv16 = f2bf(hv);
    hHi[n*64+lane] = (unsigned short)hv16;
    hLo[n*64+lane] = (unsigned short)f2bf(hv - bf2f(hv16));
    sv[2*w+q][lane] = hv;
  }
  __syncthreads();
  if (!last){
    #pragma unroll
    for (int q=0;q<2;++q){
      int n = n0 + q;
      float acc = 0.f;
      #pragma unroll 8
      for (int i = 0; i < 64; ++i) acc = fmaf(sv[2*w+q][i], b1c[i*64+lane], acc);
      hb[n*64+lane] = acc;
      mz[n*64+lane] = 0.f;
    }
  } else {
    #pragma unroll
    for (int q=0;q<2;++q){
      int n = n0 + q;
      float a0 = lin_b[lane], a1 = lin_b[64+lane];
      #pragma unroll 4
      for (int i=0;i<64;++i){
        float v = sv[2*w+q][i];
        a0 = fmaf(v, linT[i*128+lane], a0);
        a1 = fmaf(v, linT[i*128+64+lane], a1);
      }
      #pragma unroll
      for (int i=0;i<11;++i){
        float v = x[n*NNF+i];
        a0 = fmaf(v, linT[(64+i)*128+lane], a0);
        a1 = fmaf(v, linT[(64+i)*128+64+lane], a1);
      }
      h2[n*128+lane] = a0;
      h2[n*128+64+lane] = a1;
    }
  }
}

// graph ranges via binary search on sorted batch
__global__ void k_bounds(const int* __restrict__ batch, int* __restrict__ gstart){
  int b = blockIdx.x*256 + threadIdx.x;
  if (b > BG) return;
  int lo=0, hi=NN;
  while (lo < hi){ int mid=(lo+hi)>>1; if (batch[mid] < b) lo=mid+1; else hi=mid; }
  gstart[b]=lo;
}

// LSTM layer 0, reduction-split: grid 512 = (graph-pair 128) x (unit-quarter 4).
__global__ __launch_bounds__(256) void k_lstmA(
    const float* __restrict__ qstar, const float* __restrict__ h0r,
    float* __restrict__ c0, float* __restrict__ h0w,
    const f32x4* __restrict__ p0i, const f32x4* __restrict__ p0h,
    const float* __restrict__ bih0, const float* __restrict__ bhh0){
  __shared__ float sq[512], sh[256];
  __shared__ float red[8][2][32][5];
  int t = threadIdx.x;
  int gp = blockIdx.x >> 2, uq = blockIdx.x & 3;
  int g0 = gp*2;
  int u = t & 31, c = t >> 5;
  int j = uq*32 + u;
  sq[t]       = qstar[(size_t)g0*256 + t];
  sq[t + 256] = qstar[(size_t)g0*256 + 256 + t];
  sh[t]       = h0r[g0*128 + t];
  __syncthreads();
  float ai=0,af=0,ag=0,ao=0, bi=0,bf_=0,bg=0,bo=0;
  #pragma unroll 8
  for (int k = 0; k < 32; ++k){
    int i = c*32 + k;
    f32x4 w = p0i[i*128 + j];
    float x0 = sq[i], x1 = sq[256+i];
    ai=fmaf(x0,w[0],ai); af=fmaf(x0,w[1],af); ag=fmaf(x0,w[2],ag); ao=fmaf(x0,w[3],ao);
    bi=fmaf(x1,w[0],bi); bf_=fmaf(x1,w[1],bf_); bg=fmaf(x1,w[2],bg); bo=fmaf(x1,w[3],bo);
  }
  #pragma unroll 8
  for (int k = 0; k < 16; ++k){
    int i = c*16 + k;
    f32x4 w = p0h[i*128 + j];
    float x0 = sh[i], x1 = sh[128+i];
    ai=fmaf(x0,w[0],ai); af=fmaf(x0,w[1],af); ag=fmaf(x0,w[2],ag); ao=fmaf(x0,w[3],ao);
    bi=fmaf(x1,w[0],bi); bf_=fmaf(x1,w[1],bf_); bg=fmaf(x1,w[2],bg); bo=fmaf(x1,w[3],bo);
  }
  red[c][0][u][0]=ai; red[c][0][u][1]=af; red[c][0][u][2]=ag; red[c][0][u][3]=ao;
  red[c][1][u][0]=bi; red[c][1][u][1]=bf_; red[c][1][u][2]=bg; red[c][1][u][3]=bo;
  __syncthreads();
  if (t < 64){
    int g = t >> 5, uu = t & 31;
    int jj = uq*32 + uu;
    float G[4];
    #pragma unroll
    for (int q = 0; q < 4; ++q){
      float s = bih0[q*128 + jj] + bhh0[q*128 + jj];
      #pragma unroll
      for (int cc = 0; cc < 8; ++cc) s += red[cc][g][uu][q];
      G[q] = s;
    }
    int idx = (g0 + g)*128 + jj;
    float cc0 = c0[idx];
    float ig = sigm(G[0]), fg = sigm(G[1]), gg = tanhf(G[2]), og = sigm(G[3]);
    float cn = fg*cc0 + ig*gg;
    c0[idx] = cn;
    h0w[idx] = og*tanhf(cn);
  }
}

// LSTM layer 1: same decomposition.
__global__ __launch_bounds__(256) void k_lstmB(
    const float* __restrict__ h0n, const float* __restrict__ h1r,
    float* __restrict__ c1, float* __restrict__ h1w, float* __restrict__ qstar,
    const f32x4* __restrict__ p1i, const f32x4* __restrict__ p1h,
    const float* __restrict__ bih1, const float* __restrict__ bhh1){
  __shared__ float s0[256], s1[256];
  __shared__ float red[8][2][32][5];
  int t = threadIdx.x;
  int gp = blockIdx.x >> 2, uq = blockIdx.x & 3;
  int g0 = gp*2;
  int u = t & 31, c = t >> 5;
  int j = uq*32 + u;
  s0[t] = h0n[g0*128 + t];
  s1[t] = h1r[g0*128 + t];
  __syncthreads();
  float ai=0,af=0,ag=0,ao=0, bi=0,bf_=0,bg=0,bo=0;
  #pragma unroll 8
  for (int k = 0; k < 16; ++k){
    int i = c*16 + k;
    f32x4 w = p1i[i*128 + j];
    float x0 = s0[i], x1 = s0[128+i];
    ai=fmaf(x0,w[0],ai); af=fmaf(x0,w[1],af); ag=fmaf(x0,w[2],ag); ao=fmaf(x0,w[3],ao);
    bi=fmaf(x1,w[0],bi); bf_=fmaf(x1,w[1],bf_); bg=fmaf(x1,w[2],bg); bo=fmaf(x1,w[3],bo);
  }
  #pragma unroll 8
  for (int k = 0; k < 16; ++k){
    int i = c*16 + k;
    f32x4 w = p1h[i*128 + j];
    float x0 = s1[i], x1 = s1[128+i];
    ai=fmaf(x0,w[0],ai); af=fmaf(x0,w[1],af); ag=fmaf(x0,w[2],ag); ao=fmaf(x0,w[3],ao);
    bi=fmaf(x1,w[0],bi); bf_=fmaf(x1,w[1],bf_); bg=fmaf(x1,w[2],bg); bo=fmaf(x1,w[3],bo);
  }
  red[c][0][u][0]=ai; red[c][0][u][1]=af; red[c][0][u][2]=ag; red[c][0][u][3]=ao;
  red[c][1][u][0]=bi; red[c][1][u][1]=bf_; red[c][1][u][2]=bg; red[c][1][u][3]=bo;
  __syncthreads();
  if (t < 64){
    int g = t >> 5, uu = t & 31;
    int jj = uq*32 + uu;
    float G[4];
    #pragma unroll
    for (int q = 0; q < 4; ++q){
      float s = bih1[q*128 + jj] + bhh1[q*128 + jj];
      #pragma unroll
      for (int cc = 0; cc < 8; ++cc) s += red[cc][g][uu][q];
      G[q] = s;
    }
    int idx = (g0 + g)*128 + jj;
    float cc1 = c1[idx];
    float ig = sigm(G[0]), fg = sigm(G[1]), gg = tanhf(G[2]), og = sigm(G[3]);
    float cn = fg*cc1 + ig*gg;
    c1[idx] = cn;
    float hn = og*tanhf(cn);
    h1w[idx] = hn;
    qstar[(size_t)(g0 + g)*256 + jj] = hn;   // q part of q_star
  }
}

// attention readout: block = one graph, 4 waves stride the node range
__global__ __launch_bounds__(256) void k_attn2(const float* __restrict__ h2,
                       const float* __restrict__ h1,
                       const int* __restrict__ gstart, float* __restrict__ qstar){
  __shared__ float pm[4], pl[4], pr[4][128];
  int b = blockIdx.x, t = threadIdx.x, w = t>>6, lane = t&63;
  float q0 = h1[b*128+lane], q1 = h1[b*128+64+lane];
  int s = gstart[b], e = gstart[b+1];
  float mrun = -3.0e38f, l = 0.f, r0 = 0.f, r1 = 0.f;
  for (int n = s + w; n < e; n += 4){
    float v0 = h2[n*128+lane], v1 = h2[n*128+64+lane];
    float d = fmaf(v0, q0, v1*q1);
    #pragma unroll
    for (int off = 32; off; off >>= 1) d += __shfl_xor(d, off);
    float mn = fmaxf(mrun, d);
    float sc = __expf(mrun - mn);
    float ww = __expf(d - mn);
    l = l*sc + ww;
    r0 = r0*sc + ww*v0;
    r1 = r1*sc + ww*v1;
    mrun = mn;
  }
  pr[w][lane] = r0; pr[w][64+lane] = r1;
  if (lane == 0){ pm[w] = mrun; pl[w] = l; }
  __syncthreads();
  if (t < 128){
    float M = fmaxf(fmaxf(pm[0],pm[1]), fmaxf(pm[2],pm[3]));
    float L = 0.f, R = 0.f;
    #pragma unroll
    for (int ww = 0; ww < 4; ++ww){
      float sc = __expf(pm[ww] - M);
      L = fmaf(pl[ww], sc, L);
      R = fmaf(pr[ww][t], sc, R);
    }
    float inv = (L > 0.f) ? 1.f/L : 0.f;
    qstar[b*256 + 128 + t] = R*inv;
  }
}

// head: mid = relu(qstar @ w2aT + b2a); out = mid @ w2b^T + b2b. block = graph.
__global__ __launch_bounds__(512) void k_head(const float* __restrict__ qstar,
                      const float* __restrict__ w2aT, const float* __restrict__ b2a,
                      const float* __restrict__ w2b,  const float* __restrict__ b2b,
                      float* __restrict__ out){
  __shared__ float qs[256], sg[512];
  int b = blockIdx.x, j = threadIdx.x, w = j>>6, lane = j&63;
  if (j < 256) qs[j] = qstar[b*256 + j];
  __syncthreads();
  float a0 = b2a[j], a1 = 0.f, a2 = 0.f, a3 = 0.f;
  #pragma unroll
  for (int i = 0; i < 256; i += 4){
    a0 = fmaf(qs[i],   w2aT[(i)*512+j],   a0);
    a1 = fmaf(qs[i+1], w2aT[(i+1)*512+j], a1);
    a2 = fmaf(qs[i+2], w2aT[(i+2)*512+j], a2);
    a3 = fmaf(qs[i+3], w2aT[(i+3)*512+j], a3);
  }
  sg[j] = fmaxf((a0+a1)+(a2+a3), 0.f);
  __syncthreads();
  for (int jj = w; jj < NT; jj += 8){
    const float* wr = w2b + jj*512;
    float acc = 0.f;
    #pragma unroll
    for (int i = 0; i < 8; ++i) acc = fmaf(sg[lane+i*64], wr[lane+i*64], acc);
    #pragma unroll
    for (int off = 32; off; off >>= 1) acc += __shfl_xor(acc, off);
    if (lane == 0) out[b*NT+jj] = acc + b2b[jj];
  }
}

extern "C" void kernel_launch(void* const* d_in, const int* in_sizes, int n_in,
                              void* d_out, int out_size, void* d_ws, size_t ws_size,
                              hipStream_t stream) {
  const float* x    = (const float*)d_in[0];
  const float* ea   = (const float*)d_in[1];
  const int*   eidx = (const int*)d_in[2];
  const int*   batch= (const int*)d_in[3];
  const float* w1a  = (const float*)d_in[5];
  const float* b1a  = (const float*)d_in[6];
  const float* w1b  = (const float*)d_in[7];
  const float* b1b  = (const float*)d_in[8];
  const float* w1c  = (const float*)d_in[9];
  const float* b1c  = (const float*)d_in[10];
  const float* gwih = (const float*)d_in[11];
  const float* gwhh = (const float*)d_in[12];
  const float* gbih = (const float*)d_in[13];
  const float* gbhh = (const float*)d_in[14];
  const float* linw = (const float*)d_in[15];
  const float* linb = (const float*)d_in[16];
  const float* wih0 = (const float*)d_in[17];
  const float* whh0 = (const float*)d_in[18];
  const float* bih0 = (const float*)d_in[19];
  const float* bhh0 = (const float*)d_in[20];
  const float* wih1 = (const float*)d_in[21];
  const float* whh1 = (const float*)d_in[22];
  const float* bih1 = (const float*)d_in[23];
  const float* bhh1 = (const float*)d_in[24];
  const float* w2a  = (const float*)d_in[25];
  const float* b2a  = (const float*)d_in[26];
  const float* w2b  = (const float*)d_in[27];
  const float* b2b  = (const float*)d_in[28];
  float* out = (float*)d_out;

  char* p = (char*)d_ws;
  auto alloc = [&](size_t nbytes){ void* r = (void*)p; p += (nbytes + 255) & ~size_t(255); return r; };
  float* h    = (float*)alloc((size_t)NN*64*4);
  float* hb   = (float*)alloc((size_t)NN*64*4);
  float* m    = (float*)alloc((size_t)NN*64*4);
  float* h2   = (float*)alloc((size_t)NN*128*4);
  float* wihT = (float*)alloc(64*192*4);
  float* whhT = (float*)alloc(64*192*4);
  float* linT = (float*)alloc(75*128*4);
  unsigned short* w1bB = (unsigned short*)alloc(64*64*2);
  float* p0i  = (float*)alloc(131072*4);
  float* p0h  = (float*)alloc(65536*4);
  float* p1i  = (float*)alloc(65536*4);
  float* p1h  = (float*)alloc(65536*4);
  float* w2aT = (float*)alloc(256*512*4);
  // state block: qstar + h0 + c0 + h1 + c1 + h0b + h1b, contiguous zero-init
  float* qstar= (float*)alloc(256*256*4);
  float* h0   = (float*)alloc(256*128*4);
  float* c0   = (float*)alloc(256*128*4);
  float* h1s  = (float*)alloc(256*128*4);
  float* c1   = (float*)alloc(256*128*4);
  float* h0b2 = (float*)alloc(256*128*4);
  float* h1b2 = (float*)alloc(256*128*4);
  int*  gstart= (int*)alloc(257*4);
  unsigned short* e1b = (unsigned short*)alloc((size_t)NE*64*2);
  unsigned short* qtT = (unsigned short*)alloc((size_t)4096*64*2);
  unsigned short* hHi = (unsigned short*)alloc((size_t)NN*64*2);
  unsigned short* hLo = (unsigned short*)alloc((size_t)NN*64*2);
  int*  deg   = (int*)alloc((size_t)NN*4);
  int*  rowptr= (int*)alloc((size_t)(NN+1)*4);
  int*  cursor= (int*)alloc((size_t)NN*4);
  int*  csr_e = (int*)alloc((size_t)NE*4);
  u32*  P2    = (u32*)alloc((size_t)NN*2048*4);

  k_prep<<<3069, 256, 0, stream>>>(gwih, gwhh, linw, w1b, wih0, whh0, wih1, whh1,
                                   w2a, w1c, wihT, whhT, linT, w1bB, p0i, p0h,
                                   p1i, p1h, w2aT, qtT, deg, qstar);
  k_h_init<<<1250, 256, 0, stream>>>(x, h, hHi, hLo, b1c, hb, m);
  k_e1m<<<782, 256, 0, stream>>>(ea, w1a, b1a, w1bB, b1b, e1b);
  k_bounds<<<2, 256, 0, stream>>>(batch, gstart);
  k_deg<<<196, 256, 0, stream>>>(eidx, deg);
  k_scan<<<1, 256, 0, stream>>>(deg, rowptr, cursor);
  k_fill<<<196, 256, 0, stream>>>(eidx, cursor, csr_e);

  for (int t = 0; t < 3; ++t) {
    k_P3<<<79*16, 512, 0, stream>>>(hHi, hLo, qtT, P2);
    k_msg3<<<2500, 256, 0, stream>>>(rowptr, csr_e, eidx, (const u32*)e1b, P2, hb, m);
    k_gru<<<1250, 256, 0, stream>>>(m, h, hHi, hLo, wihT, whhT, gbih, gbhh, b1c, hb, m,
                                    x, linT, linb, h2, (t == 2) ? 1 : 0);
  }

  for (int s = 0; s < 3; ++s) {
    float* h0r = (s & 1) ? h0b2 : h0;
    float* h0w = (s & 1) ? h0   : h0b2;
    float* h1r = (s & 1) ? h1b2 : h1s;
    float* h1w = (s & 1) ? h1s  : h1b2;
    k_lstmA<<<512, 256, 0, stream>>>(qstar, h0r, c0, h0w, (const f32x4*)p0i,
                                     (const f32x4*)p0h, bih0, bhh0);
    k_lstmB<<<512, 256, 0, stream>>>(h0w, h1r, c1, h1w, qstar, (const f32x4*)p1i,
                                     (const f32x4*)p1h, bih1, bhh1);
    k_attn2<<<256, 256, 0, stream>>>(h2, h1w, gstart, qstar);
  }

  k_head<<<256, 512, 0, stream>>>(qstar, w2aT, b2a, w2b, b2b, out);
}

// Round 14
// 481.860 us; speedup vs baseline: 1.4099x; 1.0063x over previous
//
#include <hip/hip_runtime.h>
#include <math.h>

#define NN 10000
#define NE 50000
#define BG 256
#define NNF 11
#define NT 12

typedef unsigned int u32;
typedef __attribute__((ext_vector_type(8))) short short8v;   // 8 bf16 (4 VGPRs)
typedef __attribute__((ext_vector_type(4))) float f32x4;

__device__ __forceinline__ float sigm(float x){ return 1.0f/(1.0f+__expf(-x)); }
__device__ __forceinline__ u32 f2bf(float f){
  u32 u = __float_as_uint(f);
  return (u + 0x7fffu + ((u>>16)&1u)) >> 16;   // RNE
}
__device__ __forceinline__ float bf2f(u32 s){ return __uint_as_float(s<<16); }

// wave-per-node init: h from x, bf16 hi/lo split, hb = h@b1c, m = 0.
__global__ __launch_bounds__(256) void k_h_init(const float* __restrict__ x, float* __restrict__ h,
                         unsigned short* __restrict__ hHi, unsigned short* __restrict__ hLo,
                         const float* __restrict__ b1c, float* __restrict__ hb,
                         float* __restrict__ m){
  __shared__ float sv[8][64];
  int t = threadIdx.x, w = t>>6, lane = t&63;
  int n0 = blockIdx.x*8 + w*2;
  #pragma unroll
  for (int q = 0; q < 2; ++q){
    int n = n0 + q;
    float v = (lane < NNF) ? x[n*NNF + lane] : 0.0f;
    h[n*64+lane] = v;
    u32 hv = f2bf(v);
    hHi[n*64+lane] = (unsigned short)hv;
    hLo[n*64+lane] = (unsigned short)f2bf(v - bf2f(hv));
    sv[2*w+q][lane] = v;
  }
  __syncthreads();
  #pragma unroll
  for (int q = 0; q < 2; ++q){
    int n = n0 + q;
    float acc = 0.f;
    #pragma unroll 8
    for (int i = 0; i < 64; ++i) acc = fmaf(sv[2*w+q][i], b1c[i*64+lane], acc);
    hb[n*64+lane] = acc;
    m[n*64+lane] = 0.f;
  }
}

// weight preprocessing: transposes + bf16 builds + LSTM quadrant-packs + zeros
// + graph-range binary search (k_bounds folded in).
__global__ void k_prep(const float* __restrict__ gwih, const float* __restrict__ gwhh,
                       const float* __restrict__ linw, const float* __restrict__ w1b,
                       const float* __restrict__ wih0, const float* __restrict__ whh0,
                       const float* __restrict__ wih1, const float* __restrict__ whh1,
                       const float* __restrict__ w2a,  const float* __restrict__ w1c,
                       float* __restrict__ wihT, float* __restrict__ whhT,
                       float* __restrict__ linT, unsigned short* __restrict__ w1bB,
                       float* __restrict__ p0i, float* __restrict__ p0h,
                       float* __restrict__ p1i, float* __restrict__ p1h,
                       float* __restrict__ w2aT, unsigned short* __restrict__ qtT,
                       int* __restrict__ deg, float* __restrict__ state0,
                       const int* __restrict__ batch, int* __restrict__ gstart){
  int tid = blockIdx.x*256 + threadIdx.x;
  if (tid < 12288){ int i=tid>>6, j=tid&63; wihT[j*192+i]=gwih[tid]; return; }
  tid -= 12288;
  if (tid < 12288){ int i=tid>>6, j=tid&63; whhT[j*192+i]=gwhh[tid]; return; }
  tid -= 12288;
  if (tid < 9600){ int i=tid/75, j=tid-i*75; linT[j*128+i]=linw[tid]; return; }
  tid -= 9600;
  if (tid < 4096){ w1bB[tid] = (unsigned short)f2bf(w1b[tid]); return; }
  tid -= 4096;
  if (tid < 32768){ int i=tid>>7, j=tid&127;        // p0i[i][j] = 4 gate rows of wih0, col i
    float4 v = make_float4(wih0[(j)*256+i], wih0[(128+j)*256+i],
                           wih0[(256+j)*256+i], wih0[(384+j)*256+i]);
    *(float4*)&p0i[tid*4] = v; return; }
  tid -= 32768;
  if (tid < 16384){ int i=tid>>7, j=tid&127;
    float4 v = make_float4(whh0[(j)*128+i], whh0[(128+j)*128+i],
                           whh0[(256+j)*128+i], whh0[(384+j)*128+i]);
    *(float4*)&p0h[tid*4] = v; return; }
  tid -= 16384;
  if (tid < 16384){ int i=tid>>7, j=tid&127;
    float4 v = make_float4(wih1[(j)*128+i], wih1[(128+j)*128+i],
                           wih1[(256+j)*128+i], wih1[(384+j)*128+i]);
    *(float4*)&p1i[tid*4] = v; return; }
  tid -= 16384;
  if (tid < 16384){ int i=tid>>7, j=tid&127;
    float4 v = make_float4(whh1[(j)*128+i], whh1[(128+j)*128+i],
                           whh1[(256+j)*128+i], whh1[(384+j)*128+i]);
    *(float4*)&p1h[tid*4] = v; return; }
  tid -= 16384;
  if (tid < 131072){ int i=tid>>8, j=tid&255; w2aT[j*512+i]=w2a[tid]; return; }
  tid -= 131072;
  if (tid < 262144){ int ko=tid>>6, hh=tid&63; int k=ko>>6, o=ko&63;
                     qtT[tid] = (unsigned short)f2bf(w1c[(hh*64+o)*64+k]); return; }
  tid -= 262144;
  if (tid < NN){ deg[tid] = 0; return; }
  tid -= NN;
  if (tid < 262144){ state0[tid] = 0.f; return; }  // qstar+h0+c0+h1+c1+h0b+h1b
  tid -= 262144;
  if (tid <= BG){
    int lo=0, hi=NN;
    while (lo < hi){ int mid=(lo+hi)>>1; if (batch[mid] < tid) lo=mid+1; else hi=mid; }
    gstart[tid]=lo;
  }
}

// edge MLP via MFMA: wave = 16 edges.
__global__ __launch_bounds__(256) void k_e1m(const float* __restrict__ ea,
                     const float* __restrict__ w1a, const float* __restrict__ b1a,
                     const unsigned short* __restrict__ w1bB, const float* __restrict__ b1b,
                     unsigned short* __restrict__ e1b){
  __shared__ unsigned short sHi[4][16][64], sLo[4][16][64];   // 16 KB
  int t = threadIdx.x, w = t>>6, l = t&63;
  int c = l & 15, g = l >> 4;
  int eb = blockIdx.x*64 + w*16;
  float wa0=w1a[l*4+0], wa1=w1a[l*4+1], wa2=w1a[l*4+2], wa3=w1a[l*4+3];
  float bb1 = b1a[l];
  char* hbase = (char*)&sHi[w][0][0];
  char* lbase = (char*)&sLo[w][0][0];
  #pragma unroll
  for (int r = 0; r < 16; ++r){
    int e = eb + r; if (e >= NE) e = NE-1;
    float4 a = *(const float4*)&ea[e*4];
    float h1 = fmaxf(bb1 + a.x*wa0 + a.y*wa1 + a.z*wa2 + a.w*wa3, 0.f);
    u32 hv = f2bf(h1);
    u32 lv = f2bf(h1 - bf2f(hv));
    int wb = (r*128 + l*2) ^ ((r & 7) << 4);   // row-XOR swizzle
    *(unsigned short*)(hbase + wb) = (unsigned short)hv;
    *(unsigned short*)(lbase + wb) = (unsigned short)lv;
  }
  __syncthreads();
  int xv = (c & 7) << 4;
  int rb0 = (c*128 + g*16) ^ xv;
  int rb1 = (c*128 + 64 + g*16) ^ xv;
  short8v aH0 = *(const short8v*)(hbase + rb0);
  short8v aH1 = *(const short8v*)(hbase + rb1);
  short8v aL0 = *(const short8v*)(lbase + rb0);
  short8v aL1 = *(const short8v*)(lbase + rb1);
  f32x4 acc[4];
  #pragma unroll
  for (int f = 0; f < 4; ++f){
    const short* wrow = (const short*)w1bB + (f*16 + c)*64 + g*8;
    short8v b0 = *(const short8v*)wrow;
    short8v b1 = *(const short8v*)(wrow + 32);
    acc[f] = f32x4{0.f,0.f,0.f,0.f};
    acc[f] = __builtin_amdgcn_mfma_f32_16x16x32_bf16(aH0, b0, acc[f], 0, 0, 0);
    acc[f] = __builtin_amdgcn_mfma_f32_16x16x32_bf16(aL0, b0, acc[f], 0, 0, 0);
    acc[f] = __builtin_amdgcn_mfma_f32_16x16x32_bf16(aH1, b1, acc[f], 0, 0, 0);
    acc[f] = __builtin_amdgcn_mfma_f32_16x16x32_bf16(aL1, b1, acc[f], 0, 0, 0);
  }
  #pragma unroll
  for (int f = 0; f < 4; ++f){
    float bb2 = b1b[f*16 + c];
    #pragma unroll
    for (int r = 0; r < 4; ++r){
      int e = eb + 4*g + r;                 // C/D: row = 4*(lane>>4)+reg
      if (e < NE)
        e1b[e*64 + f*16 + c] = (unsigned short)f2bf(fmaxf(acc[f][r] + bb2, 0.f));
    }
  }
}

// P3: 512 threads = 8 waves; LDS-staged swizzled qtT tile shared by all waves.
__global__ __launch_bounds__(512) void k_P3(const unsigned short* __restrict__ hHi,
                      const unsigned short* __restrict__ hLo,
                      const unsigned short* __restrict__ qtT, u32* __restrict__ P2){
  __shared__ unsigned short sB[16384];     // 32 KB: [256 ko][64 hh] swizzled
  int t = threadIdx.x; int w = t >> 6; int l = t & 63;
  int c = l & 15, g = l >> 4;
  int nt = blockIdx.x >> 4, kt = blockIdx.x & 15;
  int kob = kt*256;
  const char* qsrc = (const char*)qtT + (size_t)kob*128;
  char* sb = (char*)sB;
  #pragma unroll
  for (int r = 0; r < 4; ++r){
    int dstb = (r*512 + t)*16;
    int srcb = dstb ^ (((dstb >> 7) & 7) << 4);    // involution pre-swizzle
    *(uint4*)(sb + dstb) = *(const uint4*)(qsrc + srcb);
  }
  int nb = nt*128 + w*16;
  int rowA = nb + c; if (rowA >= NN) rowA = NN-1;
  const short8v* aHiP = (const short8v*)((const short*)hHi + rowA*64 + g*8);
  const short8v* aLoP = (const short8v*)((const short*)hLo + rowA*64 + g*8);
  short8v aH0 = aHiP[0], aH1 = aHiP[4];
  short8v aL0 = aLoP[0], aL1 = aLoP[4];
  __syncthreads();
  int xv = (c & 7) << 4;
  f32x4 acc[16];
  #pragma unroll
  for (int f = 0; f < 16; ++f) acc[f] = f32x4{0.f,0.f,0.f,0.f};
  #pragma unroll
  for (int f = 0; f < 16; ++f){
    int baseb = f*2048 + c*128 + g*16;
    short8v b0 = *(const short8v*)(sb + (baseb ^ xv));
    short8v b1 = *(const short8v*)(sb + ((baseb + 64) ^ xv));
    acc[f] = __builtin_amdgcn_mfma_f32_16x16x32_bf16(aH0, b0, acc[f], 0, 0, 0);
    acc[f] = __builtin_amdgcn_mfma_f32_16x16x32_bf16(aL0, b0, acc[f], 0, 0, 0);
    acc[f] = __builtin_amdgcn_mfma_f32_16x16x32_bf16(aH1, b1, acc[f], 0, 0, 0);
    acc[f] = __builtin_amdgcn_mfma_f32_16x16x32_bf16(aL1, b1, acc[f], 0, 0, 0);
  }
  int k2b = kt*2;
  #pragma unroll
  for (int r = 0; r < 4; ++r){
    int node = nb + 4*g + r;
    if (node < NN){
      u32* dst = P2 + (size_t)node*2048;
      #pragma unroll
      for (int kk = 0; kk < 2; ++kk){
        uint4 v;
        v.x = f2bf(acc[8*kk+0][r]) | (f2bf(acc[8*kk+4][r]) << 16);
        v.y = f2bf(acc[8*kk+1][r]) | (f2bf(acc[8*kk+5][r]) << 16);
        v.z = f2bf(acc[8*kk+2][r]) | (f2bf(acc[8*kk+6][r]) << 16);
        v.w = f2bf(acc[8*kk+3][r]) | (f2bf(acc[8*kk+7][r]) << 16);
        *(uint4*)(dst + (k2b+kk)*64 + c*4) = v;
      }
    }
  }
}

// ---- CSR build (by src) ----
__global__ void k_deg(const int* __restrict__ ei, int* __restrict__ deg){
  int e = blockIdx.x*256 + threadIdx.x;
  if (e >= NE) return;
  atomicAdd(&deg[ei[e]], 1);
}

__global__ __launch_bounds__(256) void k_scan(const int* __restrict__ deg, int* __restrict__ rowptr,
                       int* __restrict__ cursor){
  __shared__ int part[256];
  int t = threadIdx.x;
  int base = t*40;
  int s = 0;
  for (int i = 0; i < 40; ++i){ int idx = base+i; if (idx < NN) s += deg[idx]; }
  part[t] = s;
  __syncthreads();
  for (int off = 1; off < 256; off <<= 1){
    int v = (t >= off) ? part[t-off] : 0;
    __syncthreads();
    part[t] += v;
    __syncthreads();
  }
  int run = (t == 0) ? 0 : part[t-1];
  for (int i = 0; i < 40; ++i){
    int idx = base+i;
    if (idx < NN){ rowptr[idx] = run; cursor[idx] = run; run += deg[idx]; }
  }
  if (t == 255) rowptr[NN] = part[255];
}

__global__ void k_fill(const int* __restrict__ ei, int* __restrict__ cursor, int* __restrict__ csr_e){
  int e = blockIdx.x*256 + threadIdx.x;
  if (e >= NE) return;
  int s = ei[e];
  int pos = atomicAdd(&cursor[s], 1);
  csr_e[pos] = e;
}

// message pass, CSR by src: one wave per node; register-resident P row + prefetch.
// min-waves 3 -> VGPR cap ~168: steady-state ~115 live regs fit, 1.5x TLP vs (256,2).
__global__ __launch_bounds__(256, 3) void k_msg3(const int* __restrict__ rowptr,
                       const int* __restrict__ csr_e,
                       const int* __restrict__ ei, const u32* __restrict__ e1u,
                       const u32* __restrict__ P2, const float* __restrict__ hb,
                       float* __restrict__ m){
  int t = threadIdx.x; int w = t >> 6; int l = t & 63;
  int oo = ((l & 3) << 4) | (l >> 2);       // un-permute: lane l holds output dim oo
  int n = blockIdx.x*4 + w;
  int jb = rowptr[n], je = rowptr[n+1];
  if (jb == je) return;
  float hbv = hb[n*64 + oo];
  const u32* Pn = P2 + (size_t)n*2048;
  u32 pr[32];
  #pragma unroll
  for (int k2 = 0; k2 < 32; ++k2) pr[k2] = Pn[k2*64 + l];
  int e = csr_e[jb];
  uint4 q[8];
  {
    const uint4* er4 = (const uint4*)(e1u + (size_t)e*32);
    #pragma unroll
    for (int i = 0; i < 8; ++i) q[i] = er4[i];
  }
  for (int j = jb; j < je; ++j){
    int dst = ei[NE + e];
    int en = (j+1 < je) ? csr_e[j+1] : e;
    uint4 qn[8];
    const uint4* ern = (const uint4*)(e1u + (size_t)en*32);
    #pragma unroll
    for (int i = 0; i < 8; ++i) qn[i] = ern[i];
    float a0 = hbv, a1 = 0.f, a2 = 0.f, a3 = 0.f;
    #pragma unroll
    for (int i = 0; i < 8; ++i){
      u32 w0 = q[i].x, w1 = q[i].y, w2 = q[i].z, w3 = q[i].w;
      u32 p0 = pr[4*i], p1 = pr[4*i+1], p2 = pr[4*i+2], p3 = pr[4*i+3];
      a0 = fmaf(bf2f(w0 & 0xffffu), bf2f(p0 & 0xffffu), a0);
      a0 = fmaf(bf2f(w0 >> 16),     bf2f(p0 >> 16),     a0);
      a1 = fmaf(bf2f(w1 & 0xffffu), bf2f(p1 & 0xffffu), a1);
      a1 = fmaf(bf2f(w1 >> 16),     bf2f(p1 >> 16),     a1);
      a2 = fmaf(bf2f(w2 & 0xffffu), bf2f(p2 & 0xffffu), a2);
      a2 = fmaf(bf2f(w2 >> 16),     bf2f(p2 >> 16),     a2);
      a3 = fmaf(bf2f(w3 & 0xffffu), bf2f(p3 & 0xffffu), a3);
      a3 = fmaf(bf2f(w3 >> 16),     bf2f(p3 >> 16),     a3);
    }
    atomicAdd(&m[dst*64 + oo], (a0+a1)+(a2+a3));
    #pragma unroll
    for (int i = 0; i < 8; ++i) q[i] = qn[i];
    e = en;
  }
}

// GRU: 2 nodes per wave; emits bf16 hi/lo of new h; epilogue computes either
// hb = h_new @ b1c + m = 0 (for next message pass) or, on the LAST iteration,
// h2 = cat(h_new, x) @ lin_w^T + lin_b (k_lin fused in; hb/m skipped).
__global__ __launch_bounds__(256) void k_gru(const float* __restrict__ m, float* __restrict__ h,
                     unsigned short* __restrict__ hHi, unsigned short* __restrict__ hLo,
                     const float* __restrict__ wihT, const float* __restrict__ whhT,
                     const float* __restrict__ bih, const float* __restrict__ bhh,
                     const float* __restrict__ b1c, float* __restrict__ hb,
                     float* __restrict__ mz,
                     const float* __restrict__ x, const float* __restrict__ linT,
                     const float* __restrict__ lin_b, float* __restrict__ h2, int last){
  __shared__ float sm[8][64], sh[8][64], sv[8][64];
  int t = threadIdx.x, w = t>>6, lane = t&63;
  int n0 = blockIdx.x*8 + w*2;
  sm[2*w][lane]   = m[n0*64+lane];
  sm[2*w+1][lane] = m[(n0+1)*64+lane];
  sh[2*w][lane]   = h[n0*64+lane];
  sh[2*w+1][lane] = h[(n0+1)*64+lane];
  __syncthreads();
  float gi[2][3] = {{0,0,0},{0,0,0}}, gh[2][3] = {{0,0,0},{0,0,0}};
  #pragma unroll 2
  for (int i=0;i<64;++i){
    const float* wr = wihT + i*192;
    const float* ur = whhT + i*192;
    float w0=wr[lane], w1=wr[64+lane], w2=wr[128+lane];
    float u0=ur[lane], u1=ur[64+lane], u2=ur[128+lane];
    #pragma unroll
    for (int q=0;q<2;++q){
      float mi = sm[2*w+q][i], hi = sh[2*w+q][i];
      gi[q][0]=fmaf(mi,w0,gi[q][0]); gi[q][1]=fmaf(mi,w1,gi[q][1]); gi[q][2]=fmaf(mi,w2,gi[q][2]);
      gh[q][0]=fmaf(hi,u0,gh[q][0]); gh[q][1]=fmaf(hi,u1,gh[q][1]); gh[q][2]=fmaf(hi,u2,gh[q][2]);
    }
  }
  #pragma unroll
  for (int q=0;q<2;++q){
    int n = n0 + q;
    float r  = sigm(gi[q][0]+bih[lane]      + gh[q][0]+bhh[lane]);
    float z  = sigm(gi[q][1]+bih[64+lane]   + gh[q][1]+bhh[64+lane]);
    float nn_= tanhf(gi[q][2]+bih[128+lane] + r*(gh[q][2]+bhh[128+lane]));
    float ho = sh[2*w+q][lane];
    float hv = (1.f-z)*nn_ + z*ho;
    h[n*64+lane] = hv;
    u32 hv16 = f2bf(hv);
    hHi[n*64+lane] = (unsigned short)hv16;
    hLo[n*64+lane] = (unsigned short)f2bf(hv - bf2f(hv16));
    sv[2*w+q][lane] = hv;
  }
  __syncthreads();
  if (!last){
    #pragma unroll
    for (int q=0;q<2;++q){
      int n = n0 + q;
      float acc = 0.f;
      #pragma unroll 8
      for (int i = 0; i < 64; ++i) acc = fmaf(sv[2*w+q][i], b1c[i*64+lane], acc);
      hb[n*64+lane] = acc;
      mz[n*64+lane] = 0.f;
    }
  } else {
    #pragma unroll
    for (int q=0;q<2;++q){
      int n = n0 + q;
      float a0 = lin_b[lane], a1 = lin_b[64+lane];
      #pragma unroll 4
      for (int i=0;i<64;++i){
        float v = sv[2*w+q][i];
        a0 = fmaf(v, linT[i*128+lane], a0);
        a1 = fmaf(v, linT[i*128+64+lane], a1);
      }
      #pragma unroll
      for (int i=0;i<11;++i){
        float v = x[n*NNF+i];
        a0 = fmaf(v, linT[(64+i)*128+lane], a0);
        a1 = fmaf(v, linT[(64+i)*128+64+lane], a1);
      }
      h2[n*128+lane] = a0;
      h2[n*128+64+lane] = a1;
    }
  }
}

// LSTM layer 0, reduction-split: grid 512 = (graph-pair 128) x (unit-quarter 4).
__global__ __launch_bounds__(256) void k_lstmA(
    const float* __restrict__ qstar, const float* __restrict__ h0r,
    float* __restrict__ c0, float* __restrict__ h0w,
    const f32x4* __restrict__ p0i, const f32x4* __restrict__ p0h,
    const float* __restrict__ bih0, const float* __restrict__ bhh0){
  __shared__ float sq[512], sh[256];
  __shared__ float red[8][2][32][5];
  int t = threadIdx.x;
  int gp = blockIdx.x >> 2, uq = blockIdx.x & 3;
  int g0 = gp*2;
  int u = t & 31, c = t >> 5;
  int j = uq*32 + u;
  sq[t]       = qstar[(size_t)g0*256 + t];
  sq[t + 256] = qstar[(size_t)g0*256 + 256 + t];
  sh[t]       = h0r[g0*128 + t];
  __syncthreads();
  float ai=0,af=0,ag=0,ao=0, bi=0,bf_=0,bg=0,bo=0;
  #pragma unroll 8
  for (int k = 0; k < 32; ++k){
    int i = c*32 + k;
    f32x4 w = p0i[i*128 + j];
    float x0 = sq[i], x1 = sq[256+i];
    ai=fmaf(x0,w[0],ai); af=fmaf(x0,w[1],af); ag=fmaf(x0,w[2],ag); ao=fmaf(x0,w[3],ao);
    bi=fmaf(x1,w[0],bi); bf_=fmaf(x1,w[1],bf_); bg=fmaf(x1,w[2],bg); bo=fmaf(x1,w[3],bo);
  }
  #pragma unroll 8
  for (int k = 0; k < 16; ++k){
    int i = c*16 + k;
    f32x4 w = p0h[i*128 + j];
    float x0 = sh[i], x1 = sh[128+i];
    ai=fmaf(x0,w[0],ai); af=fmaf(x0,w[1],af); ag=fmaf(x0,w[2],ag); ao=fmaf(x0,w[3],ao);
    bi=fmaf(x1,w[0],bi); bf_=fmaf(x1,w[1],bf_); bg=fmaf(x1,w[2],bg); bo=fmaf(x1,w[3],bo);
  }
  red[c][0][u][0]=ai; red[c][0][u][1]=af; red[c][0][u][2]=ag; red[c][0][u][3]=ao;
  red[c][1][u][0]=bi; red[c][1][u][1]=bf_; red[c][1][u][2]=bg; red[c][1][u][3]=bo;
  __syncthreads();
  if (t < 64){
    int g = t >> 5, uu = t & 31;
    int jj = uq*32 + uu;
    float G[4];
    #pragma unroll
    for (int q = 0; q < 4; ++q){
      float s = bih0[q*128 + jj] + bhh0[q*128 + jj];
      #pragma unroll
      for (int cc = 0; cc < 8; ++cc) s += red[cc][g][uu][q];
      G[q] = s;
    }
    int idx = (g0 + g)*128 + jj;
    float cc0 = c0[idx];
    float ig = sigm(G[0]), fg = sigm(G[1]), gg = tanhf(G[2]), og = sigm(G[3]);
    float cn = fg*cc0 + ig*gg;
    c0[idx] = cn;
    h0w[idx] = og*tanhf(cn);
  }
}

// LSTM layer 1: same decomposition.
__global__ __launch_bounds__(256) void k_lstmB(
    const float* __restrict__ h0n, const float* __restrict__ h1r,
    float* __restrict__ c1, float* __restrict__ h1w, float* __restrict__ qstar,
    const f32x4* __restrict__ p1i, const f32x4* __restrict__ p1h,
    const float* __restrict__ bih1, const float* __restrict__ bhh1){
  __shared__ float s0[256], s1[256];
  __shared__ float red[8][2][32][5];
  int t = threadIdx.x;
  int gp = blockIdx.x >> 2, uq = blockIdx.x & 3;
  int g0 = gp*2;
  int u = t & 31, c = t >> 5;
  int j = uq*32 + u;
  s0[t] = h0n[g0*128 + t];
  s1[t] = h1r[g0*128 + t];
  __syncthreads();
  float ai=0,af=0,ag=0,ao=0, bi=0,bf_=0,bg=0,bo=0;
  #pragma unroll 8
  for (int k = 0; k < 16; ++k){
    int i = c*16 + k;
    f32x4 w = p1i[i*128 + j];
    float x0 = s0[i], x1 = s0[128+i];
    ai=fmaf(x0,w[0],ai); af=fmaf(x0,w[1],af); ag=fmaf(x0,w[2],ag); ao=fmaf(x0,w[3],ao);
    bi=fmaf(x1,w[0],bi); bf_=fmaf(x1,w[1],bf_); bg=fmaf(x1,w[2],bg); bo=fmaf(x1,w[3],bo);
  }
  #pragma unroll 8
  for (int k = 0; k < 16; ++k){
    int i = c*16 + k;
    f32x4 w = p1h[i*128 + j];
    float x0 = s1[i], x1 = s1[128+i];
    ai=fmaf(x0,w[0],ai); af=fmaf(x0,w[1],af); ag=fmaf(x0,w[2],ag); ao=fmaf(x0,w[3],ao);
    bi=fmaf(x1,w[0],bi); bf_=fmaf(x1,w[1],bf_); bg=fmaf(x1,w[2],bg); bo=fmaf(x1,w[3],bo);
  }
  red[c][0][u][0]=ai; red[c][0][u][1]=af; red[c][0][u][2]=ag; red[c][0][u][3]=ao;
  red[c][1][u][0]=bi; red[c][1][u][1]=bf_; red[c][1][u][2]=bg; red[c][1][u][3]=bo;
  __syncthreads();
  if (t < 64){
    int g = t >> 5, uu = t & 31;
    int jj = uq*32 + uu;
    float G[4];
    #pragma unroll
    for (int q = 0; q < 4; ++q){
      float s = bih1[q*128 + jj] + bhh1[q*128 + jj];
      #pragma unroll
      for (int cc = 0; cc < 8; ++cc) s += red[cc][g][uu][q];
      G[q] = s;
    }
    int idx = (g0 + g)*128 + jj;
    float cc1 = c1[idx];
    float ig = sigm(G[0]), fg = sigm(G[1]), gg = tanhf(G[2]), og = sigm(G[3]);
    float cn = fg*cc1 + ig*gg;
    c1[idx] = cn;
    float hn = og*tanhf(cn);
    h1w[idx] = hn;
    qstar[(size_t)(g0 + g)*256 + jj] = hn;   // q part of q_star
  }
}

// attention readout: block = one graph, 4 waves stride the node range
__global__ __launch_bounds__(256) void k_attn2(const float* __restrict__ h2,
                       const float* __restrict__ h1,
                       const int* __restrict__ gstart, float* __restrict__ qstar){
  __shared__ float pm[4], pl[4], pr[4][128];
  int b = blockIdx.x, t = threadIdx.x, w = t>>6, lane = t&63;
  float q0 = h1[b*128+lane], q1 = h1[b*128+64+lane];
  int s = gstart[b], e = gstart[b+1];
  float mrun = -3.0e38f, l = 0.f, r0 = 0.f, r1 = 0.f;
  for (int n = s + w; n < e; n += 4){
    float v0 = h2[n*128+lane], v1 = h2[n*128+64+lane];
    float d = fmaf(v0, q0, v1*q1);
    #pragma unroll
    for (int off = 32; off; off >>= 1) d += __shfl_xor(d, off);
    float mn = fmaxf(mrun, d);
    float sc = __expf(mrun - mn);
    float ww = __expf(d - mn);
    l = l*sc + ww;
    r0 = r0*sc + ww*v0;
    r1 = r1*sc + ww*v1;
    mrun = mn;
  }
  pr[w][lane] = r0; pr[w][64+lane] = r1;
  if (lane == 0){ pm[w] = mrun; pl[w] = l; }
  __syncthreads();
  if (t < 128){
    float M = fmaxf(fmaxf(pm[0],pm[1]), fmaxf(pm[2],pm[3]));
    float L = 0.f, R = 0.f;
    #pragma unroll
    for (int ww = 0; ww < 4; ++ww){
      float sc = __expf(pm[ww] - M);
      L = fmaf(pl[ww], sc, L);
      R = fmaf(pr[ww][t], sc, R);
    }
    float inv = (L > 0.f) ? 1.f/L : 0.f;
    qstar[b*256 + 128 + t] = R*inv;
  }
}

// head: mid = relu(qstar @ w2aT + b2a); out = mid @ w2b^T + b2b. block = graph.
__global__ __launch_bounds__(512) void k_head(const float* __restrict__ qstar,
                      const float* __restrict__ w2aT, const float* __restrict__ b2a,
                      const float* __restrict__ w2b,  const float* __restrict__ b2b,
                      float* __restrict__ out){
  __shared__ float qs[256], sg[512];
  int b = blockIdx.x, j = threadIdx.x, w = j>>6, lane = j&63;
  if (j < 256) qs[j] = qstar[b*256 + j];
  __syncthreads();
  float a0 = b2a[j], a1 = 0.f, a2 = 0.f, a3 = 0.f;
  #pragma unroll
  for (int i = 0; i < 256; i += 4){
    a0 = fmaf(qs[i],   w2aT[(i)*512+j],   a0);
    a1 = fmaf(qs[i+1], w2aT[(i+1)*512+j], a1);
    a2 = fmaf(qs[i+2], w2aT[(i+2)*512+j], a2);
    a3 = fmaf(qs[i+3], w2aT[(i+3)*512+j], a3);
  }
  sg[j] = fmaxf((a0+a1)+(a2+a3), 0.f);
  __syncthreads();
  for (int jj = w; jj < NT; jj += 8){
    const float* wr = w2b + jj*512;
    float acc = 0.f;
    #pragma unroll
    for (int i = 0; i < 8; ++i) acc = fmaf(sg[lane+i*64], wr[lane+i*64], acc);
    #pragma unroll
    for (int off = 32; off; off >>= 1) acc += __shfl_xor(acc, off);
    if (lane == 0) out[b*NT+jj] = acc + b2b[jj];
  }
}

extern "C" void kernel_launch(void* const* d_in, const int* in_sizes, int n_in,
                              void* d_out, int out_size, void* d_ws, size_t ws_size,
                              hipStream_t stream) {
  const float* x    = (const float*)d_in[0];
  const float* ea   = (const float*)d_in[1];
  const int*   eidx = (const int*)d_in[2];
  const int*   batch= (const int*)d_in[3];
  const float* w1a  = (const float*)d_in[5];
  const float* b1a  = (const float*)d_in[6];
  const float* w1b  = (const float*)d_in[7];
  const float* b1b  = (const float*)d_in[8];
  const float* w1c  = (const float*)d_in[9];
  const float* b1c  = (const float*)d_in[10];
  const float* gwih = (const float*)d_in[11];
  const float* gwhh = (const float*)d_in[12];
  const float* gbih = (const float*)d_in[13];
  const float* gbhh = (const float*)d_in[14];
  const float* linw = (const float*)d_in[15];
  const float* linb = (const float*)d_in[16];
  const float* wih0 = (const float*)d_in[17];
  const float* whh0 = (const float*)d_in[18];
  const float* bih0 = (const float*)d_in[19];
  const float* bhh0 = (const float*)d_in[20];
  const float* wih1 = (const float*)d_in[21];
  const float* whh1 = (const float*)d_in[22];
  const float* bih1 = (const float*)d_in[23];
  const float* bhh1 = (const float*)d_in[24];
  const float* w2a  = (const float*)d_in[25];
  const float* b2a  = (const float*)d_in[26];
  const float* w2b  = (const float*)d_in[27];
  const float* b2b  = (const float*)d_in[28];
  float* out = (float*)d_out;

  char* p = (char*)d_ws;
  auto alloc = [&](size_t nbytes){ void* r = (void*)p; p += (nbytes + 255) & ~size_t(255); return r; };
  float* h    = (float*)alloc((size_t)NN*64*4);
  float* hb   = (float*)alloc((size_t)NN*64*4);
  float* m    = (float*)alloc((size_t)NN*64*4);
  float* h2   = (float*)alloc((size_t)NN*128*4);
  float* wihT = (float*)alloc(64*192*4);
  float* whhT = (float*)alloc(64*192*4);
  float* linT = (float*)alloc(75*128*4);
  unsigned short* w1bB = (unsigned short*)alloc(64*64*2);
  float* p0i  = (float*)alloc(131072*4);
  float* p0h  = (float*)alloc(65536*4);
  float* p1i  = (float*)alloc(65536*4);
  float* p1h  = (float*)alloc(65536*4);
  float* w2aT = (float*)alloc(256*512*4);
  // state block: qstar + h0 + c0 + h1 + c1 + h0b + h1b, contiguous zero-init
  float* qstar= (float*)alloc(256*256*4);
  float* h0   = (float*)alloc(256*128*4);
  float* c0   = (float*)alloc(256*128*4);
  float* h1s  = (float*)alloc(256*128*4);
  float* c1   = (float*)alloc(256*128*4);
  float* h0b2 = (float*)alloc(256*128*4);
  float* h1b2 = (float*)alloc(256*128*4);
  int*  gstart= (int*)alloc(257*4);
  unsigned short* e1b = (unsigned short*)alloc((size_t)NE*64*2);
  unsigned short* qtT = (unsigned short*)alloc((size_t)4096*64*2);
  unsigned short* hHi = (unsigned short*)alloc((size_t)NN*64*2);
  unsigned short* hLo = (unsigned short*)alloc((size_t)NN*64*2);
  int*  deg   = (int*)alloc((size_t)NN*4);
  int*  rowptr= (int*)alloc((size_t)(NN+1)*4);
  int*  cursor= (int*)alloc((size_t)NN*4);
  int*  csr_e = (int*)alloc((size_t)NE*4);
  u32*  P2    = (u32*)alloc((size_t)NN*2048*4);

  k_prep<<<3070, 256, 0, stream>>>(gwih, gwhh, linw, w1b, wih0, whh0, wih1, whh1,
                                   w2a, w1c, wihT, whhT, linT, w1bB, p0i, p0h,
                                   p1i, p1h, w2aT, qtT, deg, qstar, batch, gstart);
  k_h_init<<<1250, 256, 0, stream>>>(x, h, hHi, hLo, b1c, hb, m);
  k_e1m<<<782, 256, 0, stream>>>(ea, w1a, b1a, w1bB, b1b, e1b);
  k_deg<<<196, 256, 0, stream>>>(eidx, deg);
  k_scan<<<1, 256, 0, stream>>>(deg, rowptr, cursor);
  k_fill<<<196, 256, 0, stream>>>(eidx, cursor, csr_e);

  for (int t = 0; t < 3; ++t) {
    k_P3<<<79*16, 512, 0, stream>>>(hHi, hLo, qtT, P2);
    k_msg3<<<2500, 256, 0, stream>>>(rowptr, csr_e, eidx, (const u32*)e1b, P2, hb, m);
    k_gru<<<1250, 256, 0, stream>>>(m, h, hHi, hLo, wihT, whhT, gbih, gbhh, b1c, hb, m,
                                    x, linT, linb, h2, (t == 2) ? 1 : 0);
  }

  for (int s = 0; s < 3; ++s) {
    float* h0r = (s & 1) ? h0b2 : h0;
    float* h0w = (s & 1) ? h0   : h0b2;
    float* h1r = (s & 1) ? h1b2 : h1s;
    float* h1w = (s & 1) ? h1s  : h1b2;
    k_lstmA<<<512, 256, 0, stream>>>(qstar, h0r, c0, h0w, (const f32x4*)p0i,
                                     (const f32x4*)p0h, bih0, bhh0);
    k_lstmB<<<512, 256, 0, stream>>>(h0w, h1r, c1, h1w, qstar, (const f32x4*)p1i,
                                     (const f32x4*)p1h, bih1, bhh1);
    k_attn2<<<256, 256, 0, stream>>>(h2, h1w, gstart, qstar);
  }

  k_head<<<256, 512, 0, stream>>>(qstar, w2aT, b2a, w2b, b2b, out);
}